// Round 11
// baseline (475.735 us; speedup 1.0000x reference)
//
#include <hip/hip_runtime.h>

#define NN 50000
#define NP 50048            // padded rows (multiple of 128)
#define HH 128
#define CC 16
#define RRL 8
#define BB 4
#define EE 800000
#define NT (RRL * NN)       // 400000 (dst,rel) buckets, key = dst*8+rel
#define SCAN_CHUNK 2048
#define NBLK_SCAN ((NT + SCAN_CHUNK - 1) / SCAN_CHUNK)  // 196
#define KBIG 1152           // 8*128 (relations) + 128 (self-loop)
#define W0B_BLOCKS ((NN * 8 + 255) / 256)               // 1563 (16 floats/thread)
#define COMPOSE_THREADS (HH * KBIG + RRL * CC * HH + CC * HH)
#define COMPOSE_BLOCKS ((COMPOSE_THREADS + 255) / 256)  // 648
// two-phase scatter: coarse bucket = dst>>9 (512 dst = 4096 keys per bucket)
#define NC 98
#define CAP 10240           // fixed per-coarse-bucket tmp capacity (mean 8163, sigma~90)
#define SPLIT 4
#define CHUNK_E 1024        // 782 partition blocks (round-6 proven config)
#define PA_BLOCKS ((EE + CHUNK_E - 1) / CHUNK_E)        // 782
#define FRONT_BLOCKS (PA_BLOCKS + W0B_BLOCKS + COMPOSE_BLOCKS)

typedef short bf16x8_t __attribute__((ext_vector_type(8)));
typedef float f32x4_t __attribute__((ext_vector_type(4)));
typedef float f32x2_t __attribute__((ext_vector_type(2)));

__device__ __forceinline__ unsigned short f2bf(float f) {
  unsigned int x = __float_as_uint(f);
  unsigned int r = x + 0x7fffu + ((x >> 16) & 1u);
  return (unsigned short)(r >> 16);
}
__device__ __forceinline__ float bflo(unsigned int u) { return __uint_as_float(u << 16); }
__device__ __forceinline__ float bfhi(unsigned int u) {
  return __uint_as_float(u & 0xffff0000u);
}
// packed-f32 accumulate: 4x v_pk_fma_f32 instead of 8 scalar v_fma (contract=fast)
__device__ __forceinline__ void acc8v(f32x2_t* a, uint4 v, float nrm) {
  f32x2_t nn = {nrm, nrm};
  f32x2_t u0 = {bflo(v.x), bfhi(v.x)};
  f32x2_t u1 = {bflo(v.y), bfhi(v.y)};
  f32x2_t u2 = {bflo(v.z), bfhi(v.z)};
  f32x2_t u3 = {bflo(v.w), bfhi(v.w)};
  a[0] += nn * u0;
  a[1] += nn * u1;
  a[2] += nn * u2;
  a[3] += nn * u3;
}

// ---------------- prefix scan over (dst,rel) counts ----------------

__global__ __launch_bounds__(256) void scanA_kernel(const int* __restrict__ cnt,
                                                    int* __restrict__ off,
                                                    int* __restrict__ partials) {
  __shared__ int sums[256];
  int tid = threadIdx.x;
  int base = blockIdx.x * SCAN_CHUNK + tid * 8;
  int v[8];
  int s = 0;
#pragma unroll
  for (int j = 0; j < 8; ++j) {
    int idx = base + j;
    v[j] = (idx < NT) ? cnt[idx] : 0;
    s += v[j];
  }
  sums[tid] = s;
  __syncthreads();
  for (int o = 1; o < 256; o <<= 1) {
    int t = (tid >= o) ? sums[tid - o] : 0;
    __syncthreads();
    sums[tid] += t;
    __syncthreads();
  }
  int run = sums[tid] - s;
#pragma unroll
  for (int j = 0; j < 8; ++j) {
    int idx = base + j;
    if (idx < NT) off[idx] = run;
    run += v[j];
  }
  if (tid == 255) partials[blockIdx.x] = sums[255];
}

__global__ __launch_bounds__(256) void scanB_kernel(const int* __restrict__ partials,
                                                    int* __restrict__ pexcl) {
  __shared__ int sums[256];
  int tid = threadIdx.x;
  int p = (tid < NBLK_SCAN) ? partials[tid] : 0;
  sums[tid] = p;
  __syncthreads();
  for (int o = 1; o < 256; o <<= 1) {
    int t = (tid >= o) ? sums[tid - o] : 0;
    __syncthreads();
    sums[tid] += t;
    __syncthreads();
  }
  if (tid < NBLK_SCAN) pexcl[tid] = sums[tid] - p;
}

__global__ __launch_bounds__(256) void addC_kernel(int* __restrict__ off,
                                                   const int* __restrict__ pexcl,
                                                   int* __restrict__ cur) {
  int tid = threadIdx.x;
  int add = pexcl[blockIdx.x];
  int base = blockIdx.x * SCAN_CHUNK + tid * 8;
#pragma unroll
  for (int j = 0; j < 8; ++j) {
    int idx = base + j;
    if (idx < NT) {
      int v = off[idx] + add;
      off[idx] = v;
      cur[idx] = v;
    }
  }
  if (blockIdx.x == 0 && tid == 0) off[NT] = EE;
}

// ---------------- fused front kernel (round-6 sequential layout) ----------------
// blocks [0, PA_BLOCKS): edge partition (latency/atomic-bound)
// blocks [PA_BLOCKS, +W0B_BLOCKS): w0b table build (HBM-BW-bound)
// blocks [.., +COMPOSE_BLOCKS): small composed weights
// tmp is a single 16-B record/edge {key, src|z<<24, norm, 0}: ONE aligned
// uint4 store per edge.

__global__ __launch_bounds__(256) void front_kernel(
    const int* __restrict__ r, const int* __restrict__ dst, const int* __restrict__ src,
    const float* __restrict__ norm, int* __restrict__ cnt2, int* __restrict__ tmpCur,
    uint4* __restrict__ tmpR, const float* __restrict__ bases0,
    const float* __restrict__ wcomp0, unsigned short* __restrict__ w0b,
    const float* __restrict__ wcomp1, const float* __restrict__ bases1,
    const float* __restrict__ loop1, const float* __restrict__ wcomp2,
    const float* __restrict__ bases2, const float* __restrict__ loop2,
    unsigned short* __restrict__ w1big, unsigned short* __restrict__ w2t,
    unsigned short* __restrict__ loop2t) {
  __shared__ int hist[NC];
  __shared__ int run[NC];
  int tid = threadIdx.x;
  if (blockIdx.x < PA_BLOCKS) {
    // ---- edge partition: LDS hist over 98 coarse buckets, reserve run, scatter ----
    int base = blockIdx.x * CHUNK_E;
    for (int i = tid; i < NC; i += 256) hist[i] = 0;
    __syncthreads();
#pragma unroll
    for (int j = 0; j < CHUNK_E / 256; ++j) {
      int e = base + tid + j * 256;
      if (e < EE) atomicAdd(&hist[dst[e] >> 9], 1);
    }
    __syncthreads();
    if (tid < NC && hist[tid] > 0)
      run[tid] = tid * CAP + atomicAdd(&tmpCur[tid], hist[tid]);
    __syncthreads();
#pragma unroll
    for (int j = 0; j < CHUNK_E / 256; ++j) {
      int e = base + tid + j * 256;
      if (e < EE) {
        int d = dst[e], z = r[e];
        int key = d * RRL + z;
        atomicAdd(&cnt2[key], 1);
        int c = d >> 9;
        int pos = atomicAdd(&run[c], 1);
        uint4 rec;
        rec.x = (unsigned)key;
        rec.y = (unsigned)src[e] | ((unsigned)z << 24);
        rec.z = __float_as_uint(norm[e]);
        rec.w = 0u;
        tmpR[pos] = rec;
      }
    }
    return;
  }
  int bx = blockIdx.x - PA_BLOCKS;
  if (bx < W0B_BLOCKS) {
    // ---- w0b table [m][z][f]: 16 floats/thread -> 16 loads in flight ----
    int idx = bx * 256 + tid;  // m*8 + c16
    int m = idx >> 3, c16 = idx & 7;
    if (m >= NN) return;
    float4 a[BB][4];
#pragma unroll
    for (int b = 0; b < BB; ++b) {
      const float4* sp = (const float4*)(bases0 + ((size_t)b * NN + m) * HH + c16 * 16);
      a[b][0] = sp[0];
      a[b][1] = sp[1];
      a[b][2] = sp[2];
      a[b][3] = sp[3];
    }
    uint4* orow = (uint4*)w0b + (size_t)m * 128 + c16 * 2;
#pragma unroll
    for (int z = 0; z < RRL; ++z) {
      float c0 = wcomp0[z * BB + 0], c1 = wcomp0[z * BB + 1];
      float c2 = wcomp0[z * BB + 2], c3 = wcomp0[z * BB + 3];
      float e[16];
#pragma unroll
      for (int q = 0; q < 4; ++q) {
        e[q * 4 + 0] = c0 * a[0][q].x + c1 * a[1][q].x + c2 * a[2][q].x + c3 * a[3][q].x;
        e[q * 4 + 1] = c0 * a[0][q].y + c1 * a[1][q].y + c2 * a[2][q].y + c3 * a[3][q].y;
        e[q * 4 + 2] = c0 * a[0][q].z + c1 * a[1][q].z + c2 * a[2][q].z + c3 * a[3][q].z;
        e[q * 4 + 3] = c0 * a[0][q].w + c1 * a[1][q].w + c2 * a[2][q].w + c3 * a[3][q].w;
      }
      uint4 pk0, pk1;
      pk0.x = ((unsigned)f2bf(e[1]) << 16) | f2bf(e[0]);
      pk0.y = ((unsigned)f2bf(e[3]) << 16) | f2bf(e[2]);
      pk0.z = ((unsigned)f2bf(e[5]) << 16) | f2bf(e[4]);
      pk0.w = ((unsigned)f2bf(e[7]) << 16) | f2bf(e[6]);
      pk1.x = ((unsigned)f2bf(e[9]) << 16) | f2bf(e[8]);
      pk1.y = ((unsigned)f2bf(e[11]) << 16) | f2bf(e[10]);
      pk1.z = ((unsigned)f2bf(e[13]) << 16) | f2bf(e[12]);
      pk1.w = ((unsigned)f2bf(e[15]) << 16) | f2bf(e[14]);
      orow[z * 16] = pk0;
      orow[z * 16 + 1] = pk1;
    }
    return;
  }
  // ---- composed small weights ----
  int idx = (bx - W0B_BLOCKS) * 256 + tid;
  if (idx < HH * KBIG) {  // w1big[n][k]
    int n = idx / KBIG, k = idx - n * KBIG;
    float a;
    if (k < 1024) {
      int z = k >> 7, kk = k & 127;
      a = 0.f;
#pragma unroll
      for (int b = 0; b < BB; ++b)
        a += wcomp1[z * BB + b] * bases1[((size_t)b * HH + kk) * HH + n];
    } else {
      int kk = k - 1024;
      a = loop1[kk * HH + n];
    }
    w1big[idx] = f2bf(a);
    return;
  }
  int j = idx - HH * KBIG;
  if (j < RRL * CC * HH) {  // w2t[z][n][k]
    int z = j >> 11;
    int rem = j & 2047;
    int n = rem >> 7, k = rem & 127;
    float a = 0.f;
#pragma unroll
    for (int b = 0; b < BB; ++b)
      a += wcomp2[z * BB + b] * bases2[((size_t)b * HH + k) * CC + n];
    w2t[j] = f2bf(a);
    return;
  }
  j -= RRL * CC * HH;
  if (j < CC * HH) {  // loop2t[n][k]
    int n = j >> 7, k = j & 127;
    loop2t[j] = f2bf(loop2[k * CC + n]);
  }
}

// Phase B: per coarse bucket (SPLIT blocks each), read the bucket's tmp run
// sequentially, place payloads at final positions (single ep1 stream).

__global__ __launch_bounds__(256) void placeB_kernel(const int* __restrict__ tmpCur,
                                                     const uint4* __restrict__ tmpR,
                                                     int* __restrict__ cur2,
                                                     uint2* __restrict__ ep1) {
  int c = blockIdx.x / SPLIT, q = blockIdx.x % SPLIT;
  int cnt = tmpCur[c];
  int qb = (cnt * q) / SPLIT;
  int qe = (cnt * (q + 1)) / SPLIT;
  int base = c * CAP;
  for (int i = qb + threadIdx.x; i < qe; i += 256) {
    uint4 rec = tmpR[base + i];
    int pos = atomicAdd(&cur2[rec.x], 1);
    ep1[pos] = (uint2){rec.y, rec.z};
  }
}

// ---------------- layer 0: wave/dst, merged range, 4 slots x 16 lanes, 2-deep ----------------
// row = h[src]*8 + z resolved here (h is L2-resident; proven free in rounds 1/3).

__global__ __launch_bounds__(256) void l0_seg_kernel(
    const int* __restrict__ h, const int* __restrict__ off2, const uint2* __restrict__ ep1,
    const unsigned short* __restrict__ w0b, const float* __restrict__ loop0,
    const float* __restrict__ bias0, unsigned short* __restrict__ x1b) {
  int lane = threadIdx.x & 63;
  int n = blockIdx.x * 4 + (threadIdx.x >> 6);
  if (n >= NP) return;
  const int g = lane >> 4;
  const int t = lane & 15;
  f32x2_t acc[4];
#pragma unroll
  for (int j = 0; j < 4; ++j) acc[j] = (f32x2_t){0.f, 0.f};

  if (n < NN) {
    int beg = off2[n * RRL];
    int end = off2[n * RRL + RRL];
    int i = beg + g;
    uint2 p0 = {0u, 0u}, p1 = {0u, 0u};
    if (i < end) p0 = ep1[i];
    if (i + 4 < end) p1 = ep1[i + 4];
    unsigned r0 = (unsigned)h[p0.x & 0xFFFFFFu] * 8u + (p0.x >> 24);
    unsigned r1 = (unsigned)h[p1.x & 0xFFFFFFu] * 8u + (p1.x >> 24);
    while (i < end) {
      uint2 q0 = {0u, 0u}, q1 = {0u, 0u};
      if (i + 8 < end) q0 = ep1[i + 8];
      if (i + 12 < end) q1 = ep1[i + 12];
      uint4 va = *(const uint4*)(w0b + (size_t)r0 * HH + t * 8);
      uint4 vb = *(const uint4*)(w0b + (size_t)r1 * HH + t * 8);
      acc8v(acc, va, __uint_as_float(p0.y));
      acc8v(acc, vb, __uint_as_float(p1.y));
      i += 8;
      p0 = q0;
      p1 = q1;
      r0 = (unsigned)h[q0.x & 0xFFFFFFu] * 8u + (q0.x >> 24);
      r1 = (unsigned)h[q1.x & 0xFFFFFFu] * 8u + (q1.x >> 24);
    }
  }
  float* af = (float*)acc;
#pragma unroll
  for (int j = 0; j < 8; ++j) {
    af[j] += __shfl_xor(af[j], 16, 64);
    af[j] += __shfl_xor(af[j], 32, 64);
  }
  if (g != 0) return;
  uint4 o = {0u, 0u, 0u, 0u};
  if (n < NN) {
    int hn = h[n];
    float4 l0v = ((const float4*)(loop0 + (size_t)hn * HH))[t * 2];
    float4 l1v = ((const float4*)(loop0 + (size_t)hn * HH))[t * 2 + 1];
    float4 b0v = ((const float4*)bias0)[t * 2];
    float4 b1v = ((const float4*)bias0)[t * 2 + 1];
    float e0 = fmaxf(af[0] + l0v.x + b0v.x, 0.f);
    float e1 = fmaxf(af[1] + l0v.y + b0v.y, 0.f);
    float e2 = fmaxf(af[2] + l0v.z + b0v.z, 0.f);
    float e3 = fmaxf(af[3] + l0v.w + b0v.w, 0.f);
    float e4 = fmaxf(af[4] + l1v.x + b1v.x, 0.f);
    float e5 = fmaxf(af[5] + l1v.y + b1v.y, 0.f);
    float e6 = fmaxf(af[6] + l1v.z + b1v.z, 0.f);
    float e7 = fmaxf(af[7] + l1v.w + b1v.w, 0.f);
    o.x = ((unsigned)f2bf(e1) << 16) | f2bf(e0);
    o.y = ((unsigned)f2bf(e3) << 16) | f2bf(e2);
    o.z = ((unsigned)f2bf(e5) << 16) | f2bf(e4);
    o.w = ((unsigned)f2bf(e7) << 16) | f2bf(e6);
  }
  *(uint4*)(x1b + (size_t)n * HH + t * 8) = o;
}

// ---------------- layer 1 transform GEMM: T[m][z][f] = x1b @ W_z^T, t9f = x1b @ loop1^T ----

__global__ __launch_bounds__(256) void t1_gemm_kernel(const unsigned short* __restrict__ x1b,
                                                      const unsigned short* __restrict__ w1big,
                                                      unsigned short* __restrict__ T,
                                                      float* __restrict__ t9f) {
  constexpr int LP = 136;
  __shared__ unsigned short Alds[128 * LP];
  __shared__ unsigned short Blds[128 * LP];
  const int row0 = blockIdx.x * 128;
  const int tid = threadIdx.x;
  const int w = tid >> 6, lane = tid & 63;
  const int quad = lane >> 4, l15 = lane & 15;
  const int rb = w * 32;

#pragma unroll
  for (int it = 0; it < 8; ++it) {
    int flat = tid + it * 256;
    int row = flat >> 4, c8 = flat & 15;
    *(uint4*)(&Alds[row * LP + c8 * 8]) =
        *(const uint4*)(x1b + (size_t)(row0 + row) * 128 + c8 * 8);
  }

  for (int z = 0; z < 9; ++z) {
    __syncthreads();  // prior readers of Blds done (covers A load on z=0)
#pragma unroll
    for (int it = 0; it < 8; ++it) {
      int flat = tid + it * 256;
      int row = flat >> 4, c8 = flat & 15;
      *(uint4*)(&Blds[row * LP + c8 * 8]) =
          *(const uint4*)(w1big + (size_t)row * KBIG + z * 128 + c8 * 8);
    }
    __syncthreads();
    f32x4_t acc[2][8];
#pragma unroll
    for (int rt = 0; rt < 2; ++rt)
#pragma unroll
      for (int ct = 0; ct < 8; ++ct) acc[rt][ct] = (f32x4_t){0.f, 0.f, 0.f, 0.f};
#pragma unroll
    for (int ks = 0; ks < 4; ++ks) {
      int ko = ks * 32 + quad * 8;
      bf16x8_t af[2], bfr[8];
#pragma unroll
      for (int rt = 0; rt < 2; ++rt)
        af[rt] = *(const bf16x8_t*)(&Alds[(rb + rt * 16 + l15) * LP + ko]);
#pragma unroll
      for (int ct = 0; ct < 8; ++ct)
        bfr[ct] = *(const bf16x8_t*)(&Blds[(ct * 16 + l15) * LP + ko]);
#pragma unroll
      for (int rt = 0; rt < 2; ++rt)
#pragma unroll
        for (int ct = 0; ct < 8; ++ct)
          acc[rt][ct] =
              __builtin_amdgcn_mfma_f32_16x16x32_bf16(af[rt], bfr[ct], acc[rt][ct], 0, 0, 0);
    }
    if (z < 8) {
#pragma unroll
      for (int rt = 0; rt < 2; ++rt)
#pragma unroll
        for (int ct = 0; ct < 8; ++ct) {
          int f = ct * 16 + l15;
#pragma unroll
          for (int i = 0; i < 4; ++i) {
            int m = row0 + rb + rt * 16 + quad * 4 + i;
            T[((size_t)m * 8 + z) * 128 + f] = f2bf(acc[rt][ct][i]);
          }
        }
    } else {
#pragma unroll
      for (int rt = 0; rt < 2; ++rt)
#pragma unroll
        for (int ct = 0; ct < 8; ++ct) {
          int f = ct * 16 + l15;
#pragma unroll
          for (int i = 0; i < 4; ++i) {
            int m = row0 + rb + rt * 16 + quad * 4 + i;
            t9f[(size_t)m * 128 + f] = acc[rt][ct][i];
          }
        }
    }
  }
}

// ---------------- layer 1 gather: l0_seg clone over the T table ----------------

__global__ __launch_bounds__(256) void l1_seg_kernel(
    const int* __restrict__ off2, const uint2* __restrict__ ep1,
    const unsigned short* __restrict__ T, const float* __restrict__ t9f,
    const float* __restrict__ bias1, unsigned short* __restrict__ x2b) {
  int lane = threadIdx.x & 63;
  int n = blockIdx.x * 4 + (threadIdx.x >> 6);
  if (n >= NP) return;
  const int g = lane >> 4;
  const int t = lane & 15;
  f32x2_t acc[4];
#pragma unroll
  for (int j = 0; j < 4; ++j) acc[j] = (f32x2_t){0.f, 0.f};

  if (n < NN) {
    int beg = off2[n * RRL];
    int end = off2[n * RRL + RRL];
    int i = beg + g;
    uint2 p0 = {0u, 0u}, p1 = {0u, 0u};
    if (i < end) p0 = ep1[i];
    if (i + 4 < end) p1 = ep1[i + 4];
    unsigned r0 = (p0.x & 0xFFFFFFu) * 8u + (p0.x >> 24);
    unsigned r1 = (p1.x & 0xFFFFFFu) * 8u + (p1.x >> 24);
    while (i < end) {
      uint2 q0 = {0u, 0u}, q1 = {0u, 0u};
      if (i + 8 < end) q0 = ep1[i + 8];
      if (i + 12 < end) q1 = ep1[i + 12];
      uint4 va = *(const uint4*)(T + (size_t)r0 * HH + t * 8);
      uint4 vb = *(const uint4*)(T + (size_t)r1 * HH + t * 8);
      acc8v(acc, va, __uint_as_float(p0.y));
      acc8v(acc, vb, __uint_as_float(p1.y));
      i += 8;
      p0 = q0;
      p1 = q1;
      r0 = (q0.x & 0xFFFFFFu) * 8u + (q0.x >> 24);
      r1 = (q1.x & 0xFFFFFFu) * 8u + (q1.x >> 24);
    }
  }
  float* af = (float*)acc;
#pragma unroll
  for (int j = 0; j < 8; ++j) {
    af[j] += __shfl_xor(af[j], 16, 64);
    af[j] += __shfl_xor(af[j], 32, 64);
  }
  if (g != 0) return;
  uint4 o = {0u, 0u, 0u, 0u};
  if (n < NN) {
    float4 l0v = ((const float4*)(t9f + (size_t)n * HH))[t * 2];
    float4 l1v = ((const float4*)(t9f + (size_t)n * HH))[t * 2 + 1];
    float4 b0v = ((const float4*)bias1)[t * 2];
    float4 b1v = ((const float4*)bias1)[t * 2 + 1];
    float e0 = fmaxf(af[0] + l0v.x + b0v.x, 0.f);
    float e1 = fmaxf(af[1] + l0v.y + b0v.y, 0.f);
    float e2 = fmaxf(af[2] + l0v.z + b0v.z, 0.f);
    float e3 = fmaxf(af[3] + l0v.w + b0v.w, 0.f);
    float e4 = fmaxf(af[4] + l1v.x + b1v.x, 0.f);
    float e5 = fmaxf(af[5] + l1v.y + b1v.y, 0.f);
    float e6 = fmaxf(af[6] + l1v.z + b1v.z, 0.f);
    float e7 = fmaxf(af[7] + l1v.w + b1v.w, 0.f);
    o.x = ((unsigned)f2bf(e1) << 16) | f2bf(e0);
    o.y = ((unsigned)f2bf(e3) << 16) | f2bf(e2);
    o.z = ((unsigned)f2bf(e5) << 16) | f2bf(e4);
    o.w = ((unsigned)f2bf(e7) << 16) | f2bf(e6);
  }
  *(uint4*)(x2b + (size_t)n * HH + t * 8) = o;
}

// ---------------- layer-2 transform: one pass over x2b, all 8 rels + self-loop ----------------

__global__ __launch_bounds__(256) void l2_trans_kernel(
    const unsigned short* __restrict__ x2b, const unsigned short* __restrict__ w2t,
    const unsigned short* __restrict__ loop2t, const float* __restrict__ bias2,
    unsigned short* __restrict__ trans2, float* __restrict__ out) {
  constexpr int LP = 136;
  __shared__ unsigned short Alds[128 * LP];
  __shared__ unsigned short Blds[9][16 * LP];
  const int row0 = blockIdx.x * 128;
  const int tid = threadIdx.x;

#pragma unroll
  for (int it = 0; it < 8; ++it) {
    int flat = tid + it * 256;
    int row = flat >> 4, c8 = flat & 15;
    *(uint4*)(&Alds[row * LP + c8 * 8]) =
        *(const uint4*)(x2b + ((size_t)(row0 + row)) * 128 + c8 * 8);
  }
  {
    int row = tid >> 4, c8 = tid & 15;
#pragma unroll
    for (int z = 0; z < 9; ++z) {
      const unsigned short* B = (z < 8) ? w2t + (size_t)z * CC * HH : loop2t;
      *(uint4*)(&Blds[z][row * LP + c8 * 8]) = *(const uint4*)(B + row * 128 + c8 * 8);
    }
  }
  __syncthreads();

  const int w = tid >> 6, lane = tid & 63;
  const int quad = lane >> 4, l15 = lane & 15;
  const int rb = w * 32;

  for (int z = 0; z < 9; ++z) {
    f32x4_t acc[2];
    acc[0] = (f32x4_t){0.f, 0.f, 0.f, 0.f};
    acc[1] = (f32x4_t){0.f, 0.f, 0.f, 0.f};
#pragma unroll
    for (int ks = 0; ks < 4; ++ks) {
      int ko = ks * 32 + quad * 8;
      bf16x8_t af0 = *(const bf16x8_t*)(&Alds[(rb + l15) * LP + ko]);
      bf16x8_t af1 = *(const bf16x8_t*)(&Alds[(rb + 16 + l15) * LP + ko]);
      bf16x8_t bfr = *(const bf16x8_t*)(&Blds[z][l15 * LP + ko]);
      acc[0] = __builtin_amdgcn_mfma_f32_16x16x32_bf16(af0, bfr, acc[0], 0, 0, 0);
      acc[1] = __builtin_amdgcn_mfma_f32_16x16x32_bf16(af1, bfr, acc[1], 0, 0, 0);
    }
    if (z < 8) {
      unsigned short* ob = trans2 + (size_t)z * NP * CC;
#pragma unroll
      for (int rt = 0; rt < 2; ++rt)
#pragma unroll
        for (int i = 0; i < 4; ++i) {
          int m = row0 + rb + rt * 16 + quad * 4 + i;
          ob[(size_t)m * CC + l15] = f2bf(acc[rt][i]);
        }
    } else {
      float bv = bias2[l15];
#pragma unroll
      for (int rt = 0; rt < 2; ++rt)
#pragma unroll
        for (int i = 0; i < 4; ++i) {
          int m = row0 + rb + rt * 16 + quad * 4 + i;
          if (m < NN) out[(size_t)m * CC + l15] = acc[rt][i] + bv;
        }
    }
  }
}

// ---------------- layer 2 gather: wave/dst, merged range, 8 slots x 8 lanes, 2x unroll ----------------

__global__ __launch_bounds__(256) void l2_seg_kernel(const int* __restrict__ off2,
                                                     const uint2* __restrict__ ep1,
                                                     const unsigned short* __restrict__ trans2,
                                                     float* __restrict__ outp) {
  int lane = threadIdx.x & 63;
  int n = blockIdx.x * 4 + (threadIdx.x >> 6);
  if (n >= NN) return;
  const int g = lane >> 3;
  const int t = lane & 7;
  float a0 = 0.f, a1 = 0.f;
  int beg = off2[n * RRL];
  int end = off2[n * RRL + RRL];
  int i = beg + g;
  uint2 p0 = {0u, 0u}, p1 = {0u, 0u};
  if (i < end) p0 = ep1[i];
  if (i + 8 < end) p1 = ep1[i + 8];
  while (i < end) {
    uint2 q0 = {0u, 0u}, q1 = {0u, 0u};
    if (i + 16 < end) q0 = ep1[i + 16];
    if (i + 24 < end) q1 = ep1[i + 24];
    unsigned s0 = p0.x & 0xFFFFFFu, z0 = p0.x >> 24;
    unsigned s1 = p1.x & 0xFFFFFFu, z1 = p1.x >> 24;
    unsigned int u0 =
        *(const unsigned int*)(trans2 + ((size_t)z0 * NP + s0) * CC + t * 2);
    unsigned int u1 =
        *(const unsigned int*)(trans2 + ((size_t)z1 * NP + s1) * CC + t * 2);
    float na = __uint_as_float(p0.y), nb = __uint_as_float(p1.y);
    a0 = fmaf(na, bflo(u0), a0);
    a1 = fmaf(na, bfhi(u0), a1);
    a0 = fmaf(nb, bflo(u1), a0);
    a1 = fmaf(nb, bfhi(u1), a1);
    i += 16;
    p0 = q0;
    p1 = q1;
  }
  a0 += __shfl_xor(a0, 8, 64);
  a0 += __shfl_xor(a0, 16, 64);
  a0 += __shfl_xor(a0, 32, 64);
  a1 += __shfl_xor(a1, 8, 64);
  a1 += __shfl_xor(a1, 16, 64);
  a1 += __shfl_xor(a1, 32, 64);
  if (g != 0) return;
  float2* o = (float2*)(outp + (size_t)n * CC) + t;
  float2 cv = *o;
  cv.x += a0;
  cv.y += a1;
  *o = cv;
}

// ---------------- launch ----------------

extern "C" void kernel_launch(void* const* d_in, const int* in_sizes, int n_in,
                              void* d_out, int out_size, void* d_ws, size_t ws_size,
                              hipStream_t stream) {
  const int* src = (const int*)d_in[0];
  const int* dst = (const int*)d_in[1];
  const int* h = (const int*)d_in[2];
  const int* r = (const int*)d_in[3];
  const float* norm = (const float*)d_in[4];
  const float* bases0 = (const float*)d_in[5];
  const float* wcomp0 = (const float*)d_in[6];
  const float* loop0 = (const float*)d_in[7];
  const float* bias0 = (const float*)d_in[8];
  const float* bases1 = (const float*)d_in[9];
  const float* wcomp1 = (const float*)d_in[10];
  const float* loop1 = (const float*)d_in[11];
  const float* bias1 = (const float*)d_in[12];
  const float* bases2 = (const float*)d_in[13];
  const float* wcomp2 = (const float*)d_in[14];
  const float* loop2 = (const float*)d_in[15];
  const float* bias2 = (const float*)d_in[16];
  float* out = (float*)d_out;

  char* p = (char*)d_ws;
  auto alloc = [&](size_t bytes) {
    char* q = p;
    p += (bytes + 255) & ~(size_t)255;
    return q;
  };
  unsigned short* x1b = (unsigned short*)alloc((size_t)NP * HH * 2);
  unsigned short* x2b = (unsigned short*)alloc((size_t)NP * HH * 2);
  unsigned short* trans2 = (unsigned short*)alloc((size_t)RRL * NP * CC * 2);
  unsigned short* w1big = (unsigned short*)alloc((size_t)HH * KBIG * 2);
  unsigned short* w2t = (unsigned short*)alloc((size_t)RRL * CC * HH * 2);
  unsigned short* loop2t = (unsigned short*)alloc((size_t)CC * HH * 2);
  float* t9f = (float*)alloc((size_t)NP * HH * 4);
  uint2* ep1 = (uint2*)alloc((size_t)EE * 8);
  uint4* tmpR = (uint4*)alloc((size_t)NC * CAP * 16);
  int* off2 = (int*)alloc((size_t)(NT + 1) * 4);
  int* cur2 = (int*)alloc((size_t)NT * 4);
  int* cnt2 = (int*)alloc((size_t)(NT + 256) * 4);  // cnt2[NT] + tmpCur[NC] appended
  int* tmpCur = cnt2 + NT;
  int* partials = (int*)alloc(1024);
  int* pexcl = (int*)alloc(1024);
  // BIG: w0b [NN][8][128] bf16 during layer 0, then reused as T [NP][8][128] bf16
  unsigned short* BIG = (unsigned short*)alloc((size_t)RRL * NP * HH * 2);

  // ---- fused front: edge partition + hist (latency-bound), then weight prep ----
  hipMemsetAsync(cnt2, 0, (size_t)(NT + 256) * 4, stream);
  front_kernel<<<FRONT_BLOCKS, 256, 0, stream>>>(
      r, dst, src, norm, cnt2, tmpCur, tmpR, bases0, wcomp0, BIG, wcomp1, bases1, loop1,
      wcomp2, bases2, loop2, w1big, w2t, loop2t);

  // ---- scan + final placement ----
  scanA_kernel<<<NBLK_SCAN, 256, 0, stream>>>(cnt2, off2, partials);
  scanB_kernel<<<1, 256, 0, stream>>>(partials, pexcl);
  addC_kernel<<<NBLK_SCAN, 256, 0, stream>>>(off2, pexcl, cur2);
  placeB_kernel<<<NC * SPLIT, 256, 0, stream>>>(tmpCur, tmpR, cur2, ep1);

  // ---- layer 0 ----
  l0_seg_kernel<<<NP / 4, 256, 0, stream>>>(h, off2, ep1, BIG, loop0, bias0, x1b);

  // ---- layer 1: transform-then-gather (T overwrites w0b in BIG) ----
  t1_gemm_kernel<<<NP / 128, 256, 0, stream>>>(x1b, w1big, BIG, t9f);
  l1_seg_kernel<<<NP / 4, 256, 0, stream>>>(off2, ep1, BIG, t9f, bias1, x2b);

  // ---- layer 2 ----
  l2_trans_kernel<<<NP / 128, 256, 0, stream>>>(x2b, w2t, loop2t, bias2, trans2, out);
  l2_seg_kernel<<<(NN + 3) / 4, 256, 0, stream>>>(off2, ep1, trans2, out);
}

// Round 13
// 415.517 us; speedup vs baseline: 1.1449x; 1.1449x over previous
//
#include <hip/hip_runtime.h>

#define NN 50000
#define NP 50048            // padded rows (multiple of 128)
#define HH 128
#define CC 16
#define RRL 8
#define BB 4
#define EE 800000
#define NT (RRL * NN)       // 400000 (dst,rel) buckets, key = dst*8+rel
#define KBIG 1152           // 8*128 (relations) + 128 (self-loop)
#define W0B_BLOCKS ((NN * 8 + 255) / 256)               // 1563 (16 floats/thread)
#define COMPOSE_THREADS (HH * KBIG + RRL * CC * HH + CC * HH)
#define COMPOSE_BLOCKS ((COMPOSE_THREADS + 255) / 256)  // 648
// coarse bucket = dst>>7 (128 dst = 1024 keys per bucket)
#define NC 391
#define KPB 1024            // keys per coarse bucket
#define CAP 2560            // per-bucket tmp capacity (mean 2046, sigma~45)
#define CHUNK_E 1024
#define PA_BLOCKS ((EE + CHUNK_E - 1) / CHUNK_E)        // 782
#define FRONT_BLOCKS (PA_BLOCKS + W0B_BLOCKS + COMPOSE_BLOCKS)

typedef short bf16x8_t __attribute__((ext_vector_type(8)));
typedef float f32x4_t __attribute__((ext_vector_type(4)));
typedef float f32x2_t __attribute__((ext_vector_type(2)));

__device__ __forceinline__ unsigned short f2bf(float f) {
  unsigned int x = __float_as_uint(f);
  unsigned int r = x + 0x7fffu + ((x >> 16) & 1u);
  return (unsigned short)(r >> 16);
}
__device__ __forceinline__ float bflo(unsigned int u) { return __uint_as_float(u << 16); }
__device__ __forceinline__ float bfhi(unsigned int u) {
  return __uint_as_float(u & 0xffff0000u);
}
// packed-f32 accumulate: 4x v_pk_fma_f32 instead of 8 scalar v_fma (contract=fast)
__device__ __forceinline__ void acc8v(f32x2_t* a, uint4 v, float nrm) {
  f32x2_t nn = {nrm, nrm};
  f32x2_t u0 = {bflo(v.x), bfhi(v.x)};
  f32x2_t u1 = {bflo(v.y), bfhi(v.y)};
  f32x2_t u2 = {bflo(v.z), bfhi(v.z)};
  f32x2_t u3 = {bflo(v.w), bfhi(v.w)};
  a[0] += nn * u0;
  a[1] += nn * u1;
  a[2] += nn * u2;
  a[3] += nn * u3;
}

// ---------------- fused front kernel ----------------
// blocks [0, PA_BLOCKS): edge partition into coarse buckets — LDS-only atomics,
//   one uint4 record {key, src|z<<24, norm, 0} per edge. NO global fine-histogram.
// blocks [PA_BLOCKS, +W0B_BLOCKS): w0b table build (HBM-BW-bound)
// blocks [.., +COMPOSE_BLOCKS): small composed weights

__global__ __launch_bounds__(256) void front_kernel(
    const int* __restrict__ r, const int* __restrict__ dst, const int* __restrict__ src,
    const float* __restrict__ norm, int* __restrict__ tmpCur, uint4* __restrict__ tmpR,
    const float* __restrict__ bases0, const float* __restrict__ wcomp0,
    unsigned short* __restrict__ w0b, const float* __restrict__ wcomp1,
    const float* __restrict__ bases1, const float* __restrict__ loop1,
    const float* __restrict__ wcomp2, const float* __restrict__ bases2,
    const float* __restrict__ loop2, unsigned short* __restrict__ w1big,
    unsigned short* __restrict__ w2t, unsigned short* __restrict__ loop2t) {
  __shared__ int hist[NC];
  __shared__ int run[NC];
  int tid = threadIdx.x;
  if (blockIdx.x < PA_BLOCKS) {
    int base = blockIdx.x * CHUNK_E;
    for (int i = tid; i < NC; i += 256) hist[i] = 0;
    __syncthreads();
#pragma unroll
    for (int j = 0; j < CHUNK_E / 256; ++j) {
      int e = base + tid + j * 256;
      if (e < EE) atomicAdd(&hist[dst[e] >> 7], 1);
    }
    __syncthreads();
    for (int i = tid; i < NC; i += 256)
      if (hist[i] > 0) run[i] = i * CAP + atomicAdd(&tmpCur[i], hist[i]);
    __syncthreads();
#pragma unroll
    for (int j = 0; j < CHUNK_E / 256; ++j) {
      int e = base + tid + j * 256;
      if (e < EE) {
        int d = dst[e], z = r[e];
        int c = d >> 7;
        int pos = atomicAdd(&run[c], 1);
        uint4 rec;
        rec.x = (unsigned)(d * RRL + z);
        rec.y = (unsigned)src[e] | ((unsigned)z << 24);
        rec.z = __float_as_uint(norm[e]);
        rec.w = 0u;
        tmpR[pos] = rec;
      }
    }
    return;
  }
  int bx = blockIdx.x - PA_BLOCKS;
  if (bx < W0B_BLOCKS) {
    // ---- w0b table [m][z][f]: 16 floats/thread -> 16 loads in flight ----
    int idx = bx * 256 + tid;  // m*8 + c16
    int m = idx >> 3, c16 = idx & 7;
    if (m >= NN) return;
    float4 a[BB][4];
#pragma unroll
    for (int b = 0; b < BB; ++b) {
      const float4* sp = (const float4*)(bases0 + ((size_t)b * NN + m) * HH + c16 * 16);
      a[b][0] = sp[0];
      a[b][1] = sp[1];
      a[b][2] = sp[2];
      a[b][3] = sp[3];
    }
    uint4* orow = (uint4*)w0b + (size_t)m * 128 + c16 * 2;
#pragma unroll
    for (int z = 0; z < RRL; ++z) {
      float c0 = wcomp0[z * BB + 0], c1 = wcomp0[z * BB + 1];
      float c2 = wcomp0[z * BB + 2], c3 = wcomp0[z * BB + 3];
      float e[16];
#pragma unroll
      for (int q = 0; q < 4; ++q) {
        e[q * 4 + 0] = c0 * a[0][q].x + c1 * a[1][q].x + c2 * a[2][q].x + c3 * a[3][q].x;
        e[q * 4 + 1] = c0 * a[0][q].y + c1 * a[1][q].y + c2 * a[2][q].y + c3 * a[3][q].y;
        e[q * 4 + 2] = c0 * a[0][q].z + c1 * a[1][q].z + c2 * a[2][q].z + c3 * a[3][q].z;
        e[q * 4 + 3] = c0 * a[0][q].w + c1 * a[1][q].w + c2 * a[2][q].w + c3 * a[3][q].w;
      }
      uint4 pk0, pk1;
      pk0.x = ((unsigned)f2bf(e[1]) << 16) | f2bf(e[0]);
      pk0.y = ((unsigned)f2bf(e[3]) << 16) | f2bf(e[2]);
      pk0.z = ((unsigned)f2bf(e[5]) << 16) | f2bf(e[4]);
      pk0.w = ((unsigned)f2bf(e[7]) << 16) | f2bf(e[6]);
      pk1.x = ((unsigned)f2bf(e[9]) << 16) | f2bf(e[8]);
      pk1.y = ((unsigned)f2bf(e[11]) << 16) | f2bf(e[10]);
      pk1.z = ((unsigned)f2bf(e[13]) << 16) | f2bf(e[12]);
      pk1.w = ((unsigned)f2bf(e[15]) << 16) | f2bf(e[14]);
      orow[z * 16] = pk0;
      orow[z * 16 + 1] = pk1;
    }
    return;
  }
  // ---- composed small weights ----
  int idx = (bx - W0B_BLOCKS) * 256 + tid;
  if (idx < HH * KBIG) {  // w1big[n][k]
    int n = idx / KBIG, k = idx - n * KBIG;
    float a;
    if (k < 1024) {
      int z = k >> 7, kk = k & 127;
      a = 0.f;
#pragma unroll
      for (int b = 0; b < BB; ++b)
        a += wcomp1[z * BB + b] * bases1[((size_t)b * HH + kk) * HH + n];
    } else {
      int kk = k - 1024;
      a = loop1[kk * HH + n];
    }
    w1big[idx] = f2bf(a);
    return;
  }
  int j = idx - HH * KBIG;
  if (j < RRL * CC * HH) {  // w2t[z][n][k]
    int z = j >> 11;
    int rem = j & 2047;
    int n = rem >> 7, k = rem & 127;
    float a = 0.f;
#pragma unroll
    for (int b = 0; b < BB; ++b)
      a += wcomp2[z * BB + b] * bases2[((size_t)b * HH + k) * CC + n];
    w2t[j] = f2bf(a);
    return;
  }
  j -= RRL * CC * HH;
  if (j < CC * HH) {  // loop2t[n][k]
    int n = j >> 7, k = j & 127;
    loop2t[j] = f2bf(loop2[k * CC + n]);
  }
}

// ---------------- placeB: per-bucket local counting sort ----------------
// One block per coarse bucket (1024 keys, ~2046 records). Builds the fine
// histogram in LDS, prefix-scans locally, writes its off2 slice, then places
// records via LDS cursor atomics. Replaces global cnt2 atomics + 3 scan
// kernels + cur2 atomics. ep1/epw windows are single-CU (minimal write amp).
// epw = (h[src]*8+z, norm) resolved here (h is L2-resident).

__global__ __launch_bounds__(256) void placeB_kernel(const int* __restrict__ tmpCur,
                                                     const uint4* __restrict__ tmpR,
                                                     const int* __restrict__ h,
                                                     int* __restrict__ off2,
                                                     uint2* __restrict__ ep1,
                                                     uint2* __restrict__ epw) {
  __shared__ int lh[KPB];
  __shared__ int sums[256];
  const int c = blockIdx.x;
  const int tid = threadIdx.x;
  const int cnt = tmpCur[c];
  const int base = c * CAP;
  const int key0 = c * KPB;
  // coarse base = sum of tmpCur[0..c-1]
  int partial = 0;
  for (int j = tid; j < c; j += 256) partial += tmpCur[j];
  sums[tid] = partial;
  __syncthreads();
  for (int o = 1; o < 256; o <<= 1) {
    int t = (tid >= o) ? sums[tid - o] : 0;
    __syncthreads();
    sums[tid] += t;
    __syncthreads();
  }
  const int cbase = sums[255];
  // local histogram
  for (int j = tid; j < KPB; j += 256) lh[j] = 0;
  __syncthreads();
  for (int i = tid; i < cnt; i += 256)
    atomicAdd(&lh[tmpR[base + i].x - (unsigned)key0], 1);
  __syncthreads();
  // exclusive prefix over lh (4 per thread)
  int v0 = lh[tid * 4], v1 = lh[tid * 4 + 1], v2 = lh[tid * 4 + 2], v3 = lh[tid * 4 + 3];
  int s = v0 + v1 + v2 + v3;
  sums[tid] = s;
  __syncthreads();
  for (int o = 1; o < 256; o <<= 1) {
    int t = (tid >= o) ? sums[tid - o] : 0;
    __syncthreads();
    sums[tid] += t;
    __syncthreads();
  }
  int run = sums[tid] - s;
  lh[tid * 4] = run;
  lh[tid * 4 + 1] = run + v0;
  lh[tid * 4 + 2] = run + v0 + v1;
  lh[tid * 4 + 3] = run + v0 + v1 + v2;
  // write off2 slice
#pragma unroll
  for (int j = 0; j < 4; ++j) {
    int key = key0 + tid * 4 + j;
    if (key < NT) off2[key] = cbase + lh[tid * 4 + j];
  }
  if (c == 0 && tid == 0) off2[NT] = EE;
  __syncthreads();
  // place (lh becomes the cursor)
  for (int i = tid; i < cnt; i += 256) {
    uint4 rec = tmpR[base + i];
    int lk = rec.x - (unsigned)key0;
    int pos = cbase + atomicAdd(&lh[lk], 1);
    ep1[pos] = (uint2){rec.y, rec.z};
    unsigned sv = rec.y & 0xFFFFFFu, z = rec.y >> 24;
    epw[pos] = (uint2){(unsigned)h[sv] * 8u + z, rec.z};
  }
}

// ---------------- layer 0: wave/dst, merged range, 4 slots x 16 lanes, 2-deep ----------------
// epw carries the pre-resolved w0b row (h[src]*8+z) + norm (round-10 proven form).

__global__ __launch_bounds__(256) void l0_seg_kernel(
    const int* __restrict__ h, const int* __restrict__ off2, const uint2* __restrict__ epw,
    const unsigned short* __restrict__ w0b, const float* __restrict__ loop0,
    const float* __restrict__ bias0, unsigned short* __restrict__ x1b) {
  int lane = threadIdx.x & 63;
  int n = blockIdx.x * 4 + (threadIdx.x >> 6);
  if (n >= NP) return;
  const int g = lane >> 4;
  const int t = lane & 15;
  f32x2_t acc[4];
#pragma unroll
  for (int j = 0; j < 4; ++j) acc[j] = (f32x2_t){0.f, 0.f};

  if (n < NN) {
    int beg = off2[n * RRL];
    int end = off2[n * RRL + RRL];
    int i = beg + g;
    uint2 p0 = {0u, 0u}, p1 = {0u, 0u};
    if (i < end) p0 = epw[i];
    if (i + 4 < end) p1 = epw[i + 4];
    while (i < end) {
      uint2 q0 = {0u, 0u}, q1 = {0u, 0u};
      if (i + 8 < end) q0 = epw[i + 8];
      if (i + 12 < end) q1 = epw[i + 12];
      uint4 va = *(const uint4*)(w0b + (size_t)p0.x * HH + t * 8);
      uint4 vb = *(const uint4*)(w0b + (size_t)p1.x * HH + t * 8);
      acc8v(acc, va, __uint_as_float(p0.y));
      acc8v(acc, vb, __uint_as_float(p1.y));
      i += 8;
      p0 = q0;
      p1 = q1;
    }
  }
  float* af = (float*)acc;
#pragma unroll
  for (int j = 0; j < 8; ++j) {
    af[j] += __shfl_xor(af[j], 16, 64);
    af[j] += __shfl_xor(af[j], 32, 64);
  }
  if (g != 0) return;
  uint4 o = {0u, 0u, 0u, 0u};
  if (n < NN) {
    int hn = h[n];
    float4 l0v = ((const float4*)(loop0 + (size_t)hn * HH))[t * 2];
    float4 l1v = ((const float4*)(loop0 + (size_t)hn * HH))[t * 2 + 1];
    float4 b0v = ((const float4*)bias0)[t * 2];
    float4 b1v = ((const float4*)bias0)[t * 2 + 1];
    float e0 = fmaxf(af[0] + l0v.x + b0v.x, 0.f);
    float e1 = fmaxf(af[1] + l0v.y + b0v.y, 0.f);
    float e2 = fmaxf(af[2] + l0v.z + b0v.z, 0.f);
    float e3 = fmaxf(af[3] + l0v.w + b0v.w, 0.f);
    float e4 = fmaxf(af[4] + l1v.x + b1v.x, 0.f);
    float e5 = fmaxf(af[5] + l1v.y + b1v.y, 0.f);
    float e6 = fmaxf(af[6] + l1v.z + b1v.z, 0.f);
    float e7 = fmaxf(af[7] + l1v.w + b1v.w, 0.f);
    o.x = ((unsigned)f2bf(e1) << 16) | f2bf(e0);
    o.y = ((unsigned)f2bf(e3) << 16) | f2bf(e2);
    o.z = ((unsigned)f2bf(e5) << 16) | f2bf(e4);
    o.w = ((unsigned)f2bf(e7) << 16) | f2bf(e6);
  }
  *(uint4*)(x1b + (size_t)n * HH + t * 8) = o;
}

// ---------------- layer 1 transform GEMM: T[m][z][f] = x1b @ W_z^T, t9f = x1b @ loop1^T ----

__global__ __launch_bounds__(256) void t1_gemm_kernel(const unsigned short* __restrict__ x1b,
                                                      const unsigned short* __restrict__ w1big,
                                                      unsigned short* __restrict__ T,
                                                      float* __restrict__ t9f) {
  constexpr int LP = 136;
  __shared__ unsigned short Alds[128 * LP];
  __shared__ unsigned short Blds[128 * LP];
  const int row0 = blockIdx.x * 128;
  const int tid = threadIdx.x;
  const int w = tid >> 6, lane = tid & 63;
  const int quad = lane >> 4, l15 = lane & 15;
  const int rb = w * 32;

#pragma unroll
  for (int it = 0; it < 8; ++it) {
    int flat = tid + it * 256;
    int row = flat >> 4, c8 = flat & 15;
    *(uint4*)(&Alds[row * LP + c8 * 8]) =
        *(const uint4*)(x1b + (size_t)(row0 + row) * 128 + c8 * 8);
  }

  for (int z = 0; z < 9; ++z) {
    __syncthreads();  // prior readers of Blds done (covers A load on z=0)
#pragma unroll
    for (int it = 0; it < 8; ++it) {
      int flat = tid + it * 256;
      int row = flat >> 4, c8 = flat & 15;
      *(uint4*)(&Blds[row * LP + c8 * 8]) =
          *(const uint4*)(w1big + (size_t)row * KBIG + z * 128 + c8 * 8);
    }
    __syncthreads();
    f32x4_t acc[2][8];
#pragma unroll
    for (int rt = 0; rt < 2; ++rt)
#pragma unroll
      for (int ct = 0; ct < 8; ++ct) acc[rt][ct] = (f32x4_t){0.f, 0.f, 0.f, 0.f};
#pragma unroll
    for (int ks = 0; ks < 4; ++ks) {
      int ko = ks * 32 + quad * 8;
      bf16x8_t af[2], bfr[8];
#pragma unroll
      for (int rt = 0; rt < 2; ++rt)
        af[rt] = *(const bf16x8_t*)(&Alds[(rb + rt * 16 + l15) * LP + ko]);
#pragma unroll
      for (int ct = 0; ct < 8; ++ct)
        bfr[ct] = *(const bf16x8_t*)(&Blds[(ct * 16 + l15) * LP + ko]);
#pragma unroll
      for (int rt = 0; rt < 2; ++rt)
#pragma unroll
        for (int ct = 0; ct < 8; ++ct)
          acc[rt][ct] =
              __builtin_amdgcn_mfma_f32_16x16x32_bf16(af[rt], bfr[ct], acc[rt][ct], 0, 0, 0);
    }
    if (z < 8) {
#pragma unroll
      for (int rt = 0; rt < 2; ++rt)
#pragma unroll
        for (int ct = 0; ct < 8; ++ct) {
          int f = ct * 16 + l15;
#pragma unroll
          for (int i = 0; i < 4; ++i) {
            int m = row0 + rb + rt * 16 + quad * 4 + i;
            T[((size_t)m * 8 + z) * 128 + f] = f2bf(acc[rt][ct][i]);
          }
        }
    } else {
#pragma unroll
      for (int rt = 0; rt < 2; ++rt)
#pragma unroll
        for (int ct = 0; ct < 8; ++ct) {
          int f = ct * 16 + l15;
#pragma unroll
          for (int i = 0; i < 4; ++i) {
            int m = row0 + rb + rt * 16 + quad * 4 + i;
            t9f[(size_t)m * 128 + f] = acc[rt][ct][i];
          }
        }
    }
  }
}

// ---------------- layer 1 gather: l0_seg clone over the T table ----------------

__global__ __launch_bounds__(256) void l1_seg_kernel(
    const int* __restrict__ off2, const uint2* __restrict__ ep1,
    const unsigned short* __restrict__ T, const float* __restrict__ t9f,
    const float* __restrict__ bias1, unsigned short* __restrict__ x2b) {
  int lane = threadIdx.x & 63;
  int n = blockIdx.x * 4 + (threadIdx.x >> 6);
  if (n >= NP) return;
  const int g = lane >> 4;
  const int t = lane & 15;
  f32x2_t acc[4];
#pragma unroll
  for (int j = 0; j < 4; ++j) acc[j] = (f32x2_t){0.f, 0.f};

  if (n < NN) {
    int beg = off2[n * RRL];
    int end = off2[n * RRL + RRL];
    int i = beg + g;
    uint2 p0 = {0u, 0u}, p1 = {0u, 0u};
    if (i < end) p0 = ep1[i];
    if (i + 4 < end) p1 = ep1[i + 4];
    unsigned r0 = (p0.x & 0xFFFFFFu) * 8u + (p0.x >> 24);
    unsigned r1 = (p1.x & 0xFFFFFFu) * 8u + (p1.x >> 24);
    while (i < end) {
      uint2 q0 = {0u, 0u}, q1 = {0u, 0u};
      if (i + 8 < end) q0 = ep1[i + 8];
      if (i + 12 < end) q1 = ep1[i + 12];
      uint4 va = *(const uint4*)(T + (size_t)r0 * HH + t * 8);
      uint4 vb = *(const uint4*)(T + (size_t)r1 * HH + t * 8);
      acc8v(acc, va, __uint_as_float(p0.y));
      acc8v(acc, vb, __uint_as_float(p1.y));
      i += 8;
      p0 = q0;
      p1 = q1;
      r0 = (q0.x & 0xFFFFFFu) * 8u + (q0.x >> 24);
      r1 = (q1.x & 0xFFFFFFu) * 8u + (q1.x >> 24);
    }
  }
  float* af = (float*)acc;
#pragma unroll
  for (int j = 0; j < 8; ++j) {
    af[j] += __shfl_xor(af[j], 16, 64);
    af[j] += __shfl_xor(af[j], 32, 64);
  }
  if (g != 0) return;
  uint4 o = {0u, 0u, 0u, 0u};
  if (n < NN) {
    float4 l0v = ((const float4*)(t9f + (size_t)n * HH))[t * 2];
    float4 l1v = ((const float4*)(t9f + (size_t)n * HH))[t * 2 + 1];
    float4 b0v = ((const float4*)bias1)[t * 2];
    float4 b1v = ((const float4*)bias1)[t * 2 + 1];
    float e0 = fmaxf(af[0] + l0v.x + b0v.x, 0.f);
    float e1 = fmaxf(af[1] + l0v.y + b0v.y, 0.f);
    float e2 = fmaxf(af[2] + l0v.z + b0v.z, 0.f);
    float e3 = fmaxf(af[3] + l0v.w + b0v.w, 0.f);
    float e4 = fmaxf(af[4] + l1v.x + b1v.x, 0.f);
    float e5 = fmaxf(af[5] + l1v.y + b1v.y, 0.f);
    float e6 = fmaxf(af[6] + l1v.z + b1v.z, 0.f);
    float e7 = fmaxf(af[7] + l1v.w + b1v.w, 0.f);
    o.x = ((unsigned)f2bf(e1) << 16) | f2bf(e0);
    o.y = ((unsigned)f2bf(e3) << 16) | f2bf(e2);
    o.z = ((unsigned)f2bf(e5) << 16) | f2bf(e4);
    o.w = ((unsigned)f2bf(e7) << 16) | f2bf(e6);
  }
  *(uint4*)(x2b + (size_t)n * HH + t * 8) = o;
}

// ---------------- layer-2 transform: one pass over x2b, all 8 rels + self-loop ----------------

__global__ __launch_bounds__(256) void l2_trans_kernel(
    const unsigned short* __restrict__ x2b, const unsigned short* __restrict__ w2t,
    const unsigned short* __restrict__ loop2t, const float* __restrict__ bias2,
    unsigned short* __restrict__ trans2, float* __restrict__ out) {
  constexpr int LP = 136;
  __shared__ unsigned short Alds[128 * LP];
  __shared__ unsigned short Blds[9][16 * LP];
  const int row0 = blockIdx.x * 128;
  const int tid = threadIdx.x;

#pragma unroll
  for (int it = 0; it < 8; ++it) {
    int flat = tid + it * 256;
    int row = flat >> 4, c8 = flat & 15;
    *(uint4*)(&Alds[row * LP + c8 * 8]) =
        *(const uint4*)(x2b + ((size_t)(row0 + row)) * 128 + c8 * 8);
  }
  {
    int row = tid >> 4, c8 = tid & 15;
#pragma unroll
    for (int z = 0; z < 9; ++z) {
      const unsigned short* B = (z < 8) ? w2t + (size_t)z * CC * HH : loop2t;
      *(uint4*)(&Blds[z][row * LP + c8 * 8]) = *(const uint4*)(B + row * 128 + c8 * 8);
    }
  }
  __syncthreads();

  const int w = tid >> 6, lane = tid & 63;
  const int quad = lane >> 4, l15 = lane & 15;
  const int rb = w * 32;

  for (int z = 0; z < 9; ++z) {
    f32x4_t acc[2];
    acc[0] = (f32x4_t){0.f, 0.f, 0.f, 0.f};
    acc[1] = (f32x4_t){0.f, 0.f, 0.f, 0.f};
#pragma unroll
    for (int ks = 0; ks < 4; ++ks) {
      int ko = ks * 32 + quad * 8;
      bf16x8_t af0 = *(const bf16x8_t*)(&Alds[(rb + l15) * LP + ko]);
      bf16x8_t af1 = *(const bf16x8_t*)(&Alds[(rb + 16 + l15) * LP + ko]);
      bf16x8_t bfr = *(const bf16x8_t*)(&Blds[z][l15 * LP + ko]);
      acc[0] = __builtin_amdgcn_mfma_f32_16x16x32_bf16(af0, bfr, acc[0], 0, 0, 0);
      acc[1] = __builtin_amdgcn_mfma_f32_16x16x32_bf16(af1, bfr, acc[1], 0, 0, 0);
    }
    if (z < 8) {
      unsigned short* ob = trans2 + (size_t)z * NP * CC;
#pragma unroll
      for (int rt = 0; rt < 2; ++rt)
#pragma unroll
        for (int i = 0; i < 4; ++i) {
          int m = row0 + rb + rt * 16 + quad * 4 + i;
          ob[(size_t)m * CC + l15] = f2bf(acc[rt][i]);
        }
    } else {
      float bv = bias2[l15];
#pragma unroll
      for (int rt = 0; rt < 2; ++rt)
#pragma unroll
        for (int i = 0; i < 4; ++i) {
          int m = row0 + rb + rt * 16 + quad * 4 + i;
          if (m < NN) out[(size_t)m * CC + l15] = acc[rt][i] + bv;
        }
    }
  }
}

// ---------------- layer 2 gather: wave/dst, merged range, 8 slots x 8 lanes, 2x unroll ----------------

__global__ __launch_bounds__(256) void l2_seg_kernel(const int* __restrict__ off2,
                                                     const uint2* __restrict__ ep1,
                                                     const unsigned short* __restrict__ trans2,
                                                     float* __restrict__ outp) {
  int lane = threadIdx.x & 63;
  int n = blockIdx.x * 4 + (threadIdx.x >> 6);
  if (n >= NN) return;
  const int g = lane >> 3;
  const int t = lane & 7;
  float a0 = 0.f, a1 = 0.f;
  int beg = off2[n * RRL];
  int end = off2[n * RRL + RRL];
  int i = beg + g;
  uint2 p0 = {0u, 0u}, p1 = {0u, 0u};
  if (i < end) p0 = ep1[i];
  if (i + 8 < end) p1 = ep1[i + 8];
  while (i < end) {
    uint2 q0 = {0u, 0u}, q1 = {0u, 0u};
    if (i + 16 < end) q0 = ep1[i + 16];
    if (i + 24 < end) q1 = ep1[i + 24];
    unsigned s0 = p0.x & 0xFFFFFFu, z0 = p0.x >> 24;
    unsigned s1 = p1.x & 0xFFFFFFu, z1 = p1.x >> 24;
    unsigned int u0 =
        *(const unsigned int*)(trans2 + ((size_t)z0 * NP + s0) * CC + t * 2);
    unsigned int u1 =
        *(const unsigned int*)(trans2 + ((size_t)z1 * NP + s1) * CC + t * 2);
    float na = __uint_as_float(p0.y), nb = __uint_as_float(p1.y);
    a0 = fmaf(na, bflo(u0), a0);
    a1 = fmaf(na, bfhi(u0), a1);
    a0 = fmaf(nb, bflo(u1), a0);
    a1 = fmaf(nb, bfhi(u1), a1);
    i += 16;
    p0 = q0;
    p1 = q1;
  }
  a0 += __shfl_xor(a0, 8, 64);
  a0 += __shfl_xor(a0, 16, 64);
  a0 += __shfl_xor(a0, 32, 64);
  a1 += __shfl_xor(a1, 8, 64);
  a1 += __shfl_xor(a1, 16, 64);
  a1 += __shfl_xor(a1, 32, 64);
  if (g != 0) return;
  float2* o = (float2*)(outp + (size_t)n * CC) + t;
  float2 cv = *o;
  cv.x += a0;
  cv.y += a1;
  *o = cv;
}

// ---------------- launch ----------------

extern "C" void kernel_launch(void* const* d_in, const int* in_sizes, int n_in,
                              void* d_out, int out_size, void* d_ws, size_t ws_size,
                              hipStream_t stream) {
  const int* src = (const int*)d_in[0];
  const int* dst = (const int*)d_in[1];
  const int* h = (const int*)d_in[2];
  const int* r = (const int*)d_in[3];
  const float* norm = (const float*)d_in[4];
  const float* bases0 = (const float*)d_in[5];
  const float* wcomp0 = (const float*)d_in[6];
  const float* loop0 = (const float*)d_in[7];
  const float* bias0 = (const float*)d_in[8];
  const float* bases1 = (const float*)d_in[9];
  const float* wcomp1 = (const float*)d_in[10];
  const float* loop1 = (const float*)d_in[11];
  const float* bias1 = (const float*)d_in[12];
  const float* bases2 = (const float*)d_in[13];
  const float* wcomp2 = (const float*)d_in[14];
  const float* loop2 = (const float*)d_in[15];
  const float* bias2 = (const float*)d_in[16];
  float* out = (float*)d_out;

  char* p = (char*)d_ws;
  auto alloc = [&](size_t bytes) {
    char* q = p;
    p += (bytes + 255) & ~(size_t)255;
    return q;
  };
  unsigned short* x1b = (unsigned short*)alloc((size_t)NP * HH * 2);
  unsigned short* x2b = (unsigned short*)alloc((size_t)NP * HH * 2);
  unsigned short* trans2 = (unsigned short*)alloc((size_t)RRL * NP * CC * 2);
  unsigned short* w1big = (unsigned short*)alloc((size_t)HH * KBIG * 2);
  unsigned short* w2t = (unsigned short*)alloc((size_t)RRL * CC * HH * 2);
  unsigned short* loop2t = (unsigned short*)alloc((size_t)CC * HH * 2);
  float* t9f = (float*)alloc((size_t)NP * HH * 4);
  uint2* ep1 = (uint2*)alloc((size_t)EE * 8);
  uint2* epw = (uint2*)alloc((size_t)EE * 8);
  uint4* tmpR = (uint4*)alloc((size_t)NC * CAP * 16);
  int* off2 = (int*)alloc((size_t)(NT + 1) * 4);
  int* tmpCur = (int*)alloc(2048);  // 512 ints >= NC=391 (round-12 bug: was 256)
  // BIG: w0b [NN][8][128] bf16 during layer 0, then reused as T [NP][8][128] bf16
  unsigned short* BIG = (unsigned short*)alloc((size_t)RRL * NP * HH * 2);

  // ---- fused front: edge partition (LDS-only atomics) + weight prep ----
  hipMemsetAsync(tmpCur, 0, 2048, stream);
  front_kernel<<<FRONT_BLOCKS, 256, 0, stream>>>(
      r, dst, src, norm, tmpCur, tmpR, bases0, wcomp0, BIG, wcomp1, bases1, loop1,
      wcomp2, bases2, loop2, w1big, w2t, loop2t);

  // ---- per-bucket local counting sort: off2 + ep1 + epw in one kernel ----
  placeB_kernel<<<NC, 256, 0, stream>>>(tmpCur, tmpR, h, off2, ep1, epw);

  // ---- layer 0 ----
  l0_seg_kernel<<<NP / 4, 256, 0, stream>>>(h, off2, epw, BIG, loop0, bias0, x1b);

  // ---- layer 1: transform-then-gather (T overwrites w0b in BIG) ----
  t1_gemm_kernel<<<NP / 128, 256, 0, stream>>>(x1b, w1big, BIG, t9f);
  l1_seg_kernel<<<NP / 4, 256, 0, stream>>>(off2, ep1, BIG, t9f, bias1, x2b);

  // ---- layer 2 ----
  l2_trans_kernel<<<NP / 128, 256, 0, stream>>>(x2b, w2t, loop2t, bias2, trans2, out);
  l2_seg_kernel<<<(NN + 3) / 4, 256, 0, stream>>>(off2, ep1, trans2, out);
}

// Round 14
// 407.693 us; speedup vs baseline: 1.1669x; 1.0192x over previous
//
#include <hip/hip_runtime.h>

#define NN 50000
#define NP 50048            // padded rows (multiple of 128)
#define HH 128
#define CC 16
#define RRL 8
#define BB 4
#define EE 800000
#define NT (RRL * NN)       // 400000 (dst,rel) buckets, key = dst*8+rel
#define KBIG 1152           // 8*128 (relations) + 128 (self-loop)
#define W0B_BLOCKS ((NN * 8 + 255) / 256)               // 1563 (16 floats/thread)
#define COMPOSE_THREADS (HH * KBIG + RRL * CC * HH + CC * HH)
#define COMPOSE_BLOCKS ((COMPOSE_THREADS + 255) / 256)  // 648
// coarse bucket = dst>>7 (128 dst = 1024 keys per bucket)
#define NC 391
#define KPB 1024            // keys per coarse bucket
#define CAP 2560            // per-bucket tmp capacity (mean 2046, sigma~45)
#define CHUNK_E 2048
#define EPT (CHUNK_E / 256) // 8 edges per thread
#define PA_BLOCKS ((EE + CHUNK_E - 1) / CHUNK_E)        // 391
#define FRONT_BLOCKS (PA_BLOCKS + W0B_BLOCKS + COMPOSE_BLOCKS)

typedef short bf16x8_t __attribute__((ext_vector_type(8)));
typedef float f32x4_t __attribute__((ext_vector_type(4)));
typedef float f32x2_t __attribute__((ext_vector_type(2)));

__device__ __forceinline__ unsigned short f2bf(float f) {
  unsigned int x = __float_as_uint(f);
  unsigned int r = x + 0x7fffu + ((x >> 16) & 1u);
  return (unsigned short)(r >> 16);
}
__device__ __forceinline__ float bflo(unsigned int u) { return __uint_as_float(u << 16); }
__device__ __forceinline__ float bfhi(unsigned int u) {
  return __uint_as_float(u & 0xffff0000u);
}
// packed-f32 accumulate: 4x v_pk_fma_f32 instead of 8 scalar v_fma (contract=fast)
__device__ __forceinline__ void acc8v(f32x2_t* a, uint4 v, float nrm) {
  f32x2_t nn = {nrm, nrm};
  f32x2_t u0 = {bflo(v.x), bfhi(v.x)};
  f32x2_t u1 = {bflo(v.y), bfhi(v.y)};
  f32x2_t u2 = {bflo(v.z), bfhi(v.z)};
  f32x2_t u3 = {bflo(v.w), bfhi(v.w)};
  a[0] += nn * u0;
  a[1] += nn * u1;
  a[2] += nn * u2;
  a[3] += nn * u3;
}

// ---------------- fused front kernel ----------------
// blocks [0, PA_BLOCKS): edge partition into coarse buckets — LDS-only atomics,
//   one uint4 record {key, src|z<<24, norm, 0} per edge. dst register-cached
//   across the hist and scatter passes.
// blocks [PA_BLOCKS, +W0B_BLOCKS): w0b table build (HBM-BW-bound)
// blocks [.., +COMPOSE_BLOCKS): small composed weights

__global__ __launch_bounds__(256) void front_kernel(
    const int* __restrict__ r, const int* __restrict__ dst, const int* __restrict__ src,
    const float* __restrict__ norm, int* __restrict__ tmpCur, uint4* __restrict__ tmpR,
    const float* __restrict__ bases0, const float* __restrict__ wcomp0,
    unsigned short* __restrict__ w0b, const float* __restrict__ wcomp1,
    const float* __restrict__ bases1, const float* __restrict__ loop1,
    const float* __restrict__ wcomp2, const float* __restrict__ bases2,
    const float* __restrict__ loop2, unsigned short* __restrict__ w1big,
    unsigned short* __restrict__ w2t, unsigned short* __restrict__ loop2t) {
  __shared__ int hist[NC];
  __shared__ int run[NC];
  int tid = threadIdx.x;
  if (blockIdx.x < PA_BLOCKS) {
    int base = blockIdx.x * CHUNK_E;
    for (int i = tid; i < NC; i += 256) hist[i] = 0;
    __syncthreads();
    int dcache[EPT];
#pragma unroll
    for (int j = 0; j < EPT; ++j) {
      int e = base + tid + j * 256;
      dcache[j] = (e < EE) ? dst[e] : -1;
      if (e < EE) atomicAdd(&hist[dcache[j] >> 7], 1);
    }
    __syncthreads();
    for (int i = tid; i < NC; i += 256)
      if (hist[i] > 0) run[i] = i * CAP + atomicAdd(&tmpCur[i], hist[i]);
    __syncthreads();
#pragma unroll
    for (int j = 0; j < EPT; ++j) {
      int e = base + tid + j * 256;
      if (e < EE) {
        int d = dcache[j], z = r[e];
        int c = d >> 7;
        int pos = atomicAdd(&run[c], 1);
        uint4 rec;
        rec.x = (unsigned)(d * RRL + z);
        rec.y = (unsigned)src[e] | ((unsigned)z << 24);
        rec.z = __float_as_uint(norm[e]);
        rec.w = 0u;
        tmpR[pos] = rec;
      }
    }
    return;
  }
  int bx = blockIdx.x - PA_BLOCKS;
  if (bx < W0B_BLOCKS) {
    // ---- w0b table [m][z][f]: 16 floats/thread -> 16 loads in flight ----
    int idx = bx * 256 + tid;  // m*8 + c16
    int m = idx >> 3, c16 = idx & 7;
    if (m >= NN) return;
    float4 a[BB][4];
#pragma unroll
    for (int b = 0; b < BB; ++b) {
      const float4* sp = (const float4*)(bases0 + ((size_t)b * NN + m) * HH + c16 * 16);
      a[b][0] = sp[0];
      a[b][1] = sp[1];
      a[b][2] = sp[2];
      a[b][3] = sp[3];
    }
    uint4* orow = (uint4*)w0b + (size_t)m * 128 + c16 * 2;
#pragma unroll
    for (int z = 0; z < RRL; ++z) {
      float c0 = wcomp0[z * BB + 0], c1 = wcomp0[z * BB + 1];
      float c2 = wcomp0[z * BB + 2], c3 = wcomp0[z * BB + 3];
      float e[16];
#pragma unroll
      for (int q = 0; q < 4; ++q) {
        e[q * 4 + 0] = c0 * a[0][q].x + c1 * a[1][q].x + c2 * a[2][q].x + c3 * a[3][q].x;
        e[q * 4 + 1] = c0 * a[0][q].y + c1 * a[1][q].y + c2 * a[2][q].y + c3 * a[3][q].y;
        e[q * 4 + 2] = c0 * a[0][q].z + c1 * a[1][q].z + c2 * a[2][q].z + c3 * a[3][q].z;
        e[q * 4 + 3] = c0 * a[0][q].w + c1 * a[1][q].w + c2 * a[2][q].w + c3 * a[3][q].w;
      }
      uint4 pk0, pk1;
      pk0.x = ((unsigned)f2bf(e[1]) << 16) | f2bf(e[0]);
      pk0.y = ((unsigned)f2bf(e[3]) << 16) | f2bf(e[2]);
      pk0.z = ((unsigned)f2bf(e[5]) << 16) | f2bf(e[4]);
      pk0.w = ((unsigned)f2bf(e[7]) << 16) | f2bf(e[6]);
      pk1.x = ((unsigned)f2bf(e[9]) << 16) | f2bf(e[8]);
      pk1.y = ((unsigned)f2bf(e[11]) << 16) | f2bf(e[10]);
      pk1.z = ((unsigned)f2bf(e[13]) << 16) | f2bf(e[12]);
      pk1.w = ((unsigned)f2bf(e[15]) << 16) | f2bf(e[14]);
      orow[z * 16] = pk0;
      orow[z * 16 + 1] = pk1;
    }
    return;
  }
  // ---- composed small weights ----
  int idx = (bx - W0B_BLOCKS) * 256 + tid;
  if (idx < HH * KBIG) {  // w1big[n][k]
    int n = idx / KBIG, k = idx - n * KBIG;
    float a;
    if (k < 1024) {
      int z = k >> 7, kk = k & 127;
      a = 0.f;
#pragma unroll
      for (int b = 0; b < BB; ++b)
        a += wcomp1[z * BB + b] * bases1[((size_t)b * HH + kk) * HH + n];
    } else {
      int kk = k - 1024;
      a = loop1[kk * HH + n];
    }
    w1big[idx] = f2bf(a);
    return;
  }
  int j = idx - HH * KBIG;
  if (j < RRL * CC * HH) {  // w2t[z][n][k]
    int z = j >> 11;
    int rem = j & 2047;
    int n = rem >> 7, k = rem & 127;
    float a = 0.f;
#pragma unroll
    for (int b = 0; b < BB; ++b)
      a += wcomp2[z * BB + b] * bases2[((size_t)b * HH + k) * CC + n];
    w2t[j] = f2bf(a);
    return;
  }
  j -= RRL * CC * HH;
  if (j < CC * HH) {  // loop2t[n][k]
    int n = j >> 7, k = j & 127;
    loop2t[j] = f2bf(loop2[k * CC + n]);
  }
}

// ---------------- placeB: per-bucket local counting sort ----------------
// One block per coarse bucket (1024 keys, ~2046 records). Builds the fine
// histogram in LDS, prefix-scans locally, writes its off2 slice, then places
// records via LDS cursor atomics. ep1/epw windows are single-CU.
// epw = (h[src]*8+z, norm) resolved here (h is L2-resident).

__global__ __launch_bounds__(256) void placeB_kernel(const int* __restrict__ tmpCur,
                                                     const uint4* __restrict__ tmpR,
                                                     const int* __restrict__ h,
                                                     int* __restrict__ off2,
                                                     uint2* __restrict__ ep1,
                                                     uint2* __restrict__ epw) {
  __shared__ int lh[KPB];
  __shared__ int sums[256];
  const int c = blockIdx.x;
  const int tid = threadIdx.x;
  const int cnt = tmpCur[c];
  const int base = c * CAP;
  const int key0 = c * KPB;
  // coarse base = sum of tmpCur[0..c-1]
  int partial = 0;
  for (int j = tid; j < c; j += 256) partial += tmpCur[j];
  sums[tid] = partial;
  __syncthreads();
  for (int o = 1; o < 256; o <<= 1) {
    int t = (tid >= o) ? sums[tid - o] : 0;
    __syncthreads();
    sums[tid] += t;
    __syncthreads();
  }
  const int cbase = sums[255];
  // local histogram
  for (int j = tid; j < KPB; j += 256) lh[j] = 0;
  __syncthreads();
  for (int i = tid; i < cnt; i += 256)
    atomicAdd(&lh[tmpR[base + i].x - (unsigned)key0], 1);
  __syncthreads();
  // exclusive prefix over lh (4 per thread)
  int v0 = lh[tid * 4], v1 = lh[tid * 4 + 1], v2 = lh[tid * 4 + 2], v3 = lh[tid * 4 + 3];
  int s = v0 + v1 + v2 + v3;
  sums[tid] = s;
  __syncthreads();
  for (int o = 1; o < 256; o <<= 1) {
    int t = (tid >= o) ? sums[tid - o] : 0;
    __syncthreads();
    sums[tid] += t;
    __syncthreads();
  }
  int run = sums[tid] - s;
  lh[tid * 4] = run;
  lh[tid * 4 + 1] = run + v0;
  lh[tid * 4 + 2] = run + v0 + v1;
  lh[tid * 4 + 3] = run + v0 + v1 + v2;
  // write off2 slice
#pragma unroll
  for (int j = 0; j < 4; ++j) {
    int key = key0 + tid * 4 + j;
    if (key < NT) off2[key] = cbase + lh[tid * 4 + j];
  }
  if (c == 0 && tid == 0) off2[NT] = EE;
  __syncthreads();
  // place (lh becomes the cursor)
  for (int i = tid; i < cnt; i += 256) {
    uint4 rec = tmpR[base + i];
    int lk = rec.x - (unsigned)key0;
    int pos = cbase + atomicAdd(&lh[lk], 1);
    ep1[pos] = (uint2){rec.y, rec.z};
    unsigned sv = rec.y & 0xFFFFFFu, z = rec.y >> 24;
    epw[pos] = (uint2){(unsigned)h[sv] * 8u + z, rec.z};
  }
}

// ---------------- layer 0: wave/dst, merged range, 4 slots x 16 lanes, 2-deep ----------------
// epw carries the pre-resolved w0b row (h[src]*8+z) + norm (round-10 proven form).

__global__ __launch_bounds__(256) void l0_seg_kernel(
    const int* __restrict__ h, const int* __restrict__ off2, const uint2* __restrict__ epw,
    const unsigned short* __restrict__ w0b, const float* __restrict__ loop0,
    const float* __restrict__ bias0, unsigned short* __restrict__ x1b) {
  int lane = threadIdx.x & 63;
  int n = blockIdx.x * 4 + (threadIdx.x >> 6);
  if (n >= NP) return;
  const int g = lane >> 4;
  const int t = lane & 15;
  f32x2_t acc[4];
#pragma unroll
  for (int j = 0; j < 4; ++j) acc[j] = (f32x2_t){0.f, 0.f};

  if (n < NN) {
    int beg = off2[n * RRL];
    int end = off2[n * RRL + RRL];
    int i = beg + g;
    uint2 p0 = {0u, 0u}, p1 = {0u, 0u};
    if (i < end) p0 = epw[i];
    if (i + 4 < end) p1 = epw[i + 4];
    while (i < end) {
      uint2 q0 = {0u, 0u}, q1 = {0u, 0u};
      if (i + 8 < end) q0 = epw[i + 8];
      if (i + 12 < end) q1 = epw[i + 12];
      uint4 va = *(const uint4*)(w0b + (size_t)p0.x * HH + t * 8);
      uint4 vb = *(const uint4*)(w0b + (size_t)p1.x * HH + t * 8);
      acc8v(acc, va, __uint_as_float(p0.y));
      acc8v(acc, vb, __uint_as_float(p1.y));
      i += 8;
      p0 = q0;
      p1 = q1;
    }
  }
  float* af = (float*)acc;
#pragma unroll
  for (int j = 0; j < 8; ++j) {
    af[j] += __shfl_xor(af[j], 16, 64);
    af[j] += __shfl_xor(af[j], 32, 64);
  }
  if (g != 0) return;
  uint4 o = {0u, 0u, 0u, 0u};
  if (n < NN) {
    int hn = h[n];
    float4 l0v = ((const float4*)(loop0 + (size_t)hn * HH))[t * 2];
    float4 l1v = ((const float4*)(loop0 + (size_t)hn * HH))[t * 2 + 1];
    float4 b0v = ((const float4*)bias0)[t * 2];
    float4 b1v = ((const float4*)bias0)[t * 2 + 1];
    float e0 = fmaxf(af[0] + l0v.x + b0v.x, 0.f);
    float e1 = fmaxf(af[1] + l0v.y + b0v.y, 0.f);
    float e2 = fmaxf(af[2] + l0v.z + b0v.z, 0.f);
    float e3 = fmaxf(af[3] + l0v.w + b0v.w, 0.f);
    float e4 = fmaxf(af[4] + l1v.x + b1v.x, 0.f);
    float e5 = fmaxf(af[5] + l1v.y + b1v.y, 0.f);
    float e6 = fmaxf(af[6] + l1v.z + b1v.z, 0.f);
    float e7 = fmaxf(af[7] + l1v.w + b1v.w, 0.f);
    o.x = ((unsigned)f2bf(e1) << 16) | f2bf(e0);
    o.y = ((unsigned)f2bf(e3) << 16) | f2bf(e2);
    o.z = ((unsigned)f2bf(e5) << 16) | f2bf(e4);
    o.w = ((unsigned)f2bf(e7) << 16) | f2bf(e6);
  }
  *(uint4*)(x1b + (size_t)n * HH + t * 8) = o;
}

// ---------------- layer 1 transform GEMM: T[m][z][f] = x1b @ W_z^T, t9f = x1b @ loop1^T ----

__global__ __launch_bounds__(256) void t1_gemm_kernel(const unsigned short* __restrict__ x1b,
                                                      const unsigned short* __restrict__ w1big,
                                                      unsigned short* __restrict__ T,
                                                      float* __restrict__ t9f) {
  constexpr int LP = 136;
  __shared__ unsigned short Alds[128 * LP];
  __shared__ unsigned short Blds[128 * LP];
  const int row0 = blockIdx.x * 128;
  const int tid = threadIdx.x;
  const int w = tid >> 6, lane = tid & 63;
  const int quad = lane >> 4, l15 = lane & 15;
  const int rb = w * 32;

#pragma unroll
  for (int it = 0; it < 8; ++it) {
    int flat = tid + it * 256;
    int row = flat >> 4, c8 = flat & 15;
    *(uint4*)(&Alds[row * LP + c8 * 8]) =
        *(const uint4*)(x1b + (size_t)(row0 + row) * 128 + c8 * 8);
  }

  for (int z = 0; z < 9; ++z) {
    __syncthreads();  // prior readers of Blds done (covers A load on z=0)
#pragma unroll
    for (int it = 0; it < 8; ++it) {
      int flat = tid + it * 256;
      int row = flat >> 4, c8 = flat & 15;
      *(uint4*)(&Blds[row * LP + c8 * 8]) =
          *(const uint4*)(w1big + (size_t)row * KBIG + z * 128 + c8 * 8);
    }
    __syncthreads();
    f32x4_t acc[2][8];
#pragma unroll
    for (int rt = 0; rt < 2; ++rt)
#pragma unroll
      for (int ct = 0; ct < 8; ++ct) acc[rt][ct] = (f32x4_t){0.f, 0.f, 0.f, 0.f};
#pragma unroll
    for (int ks = 0; ks < 4; ++ks) {
      int ko = ks * 32 + quad * 8;
      bf16x8_t af[2], bfr[8];
#pragma unroll
      for (int rt = 0; rt < 2; ++rt)
        af[rt] = *(const bf16x8_t*)(&Alds[(rb + rt * 16 + l15) * LP + ko]);
#pragma unroll
      for (int ct = 0; ct < 8; ++ct)
        bfr[ct] = *(const bf16x8_t*)(&Blds[(ct * 16 + l15) * LP + ko]);
#pragma unroll
      for (int rt = 0; rt < 2; ++rt)
#pragma unroll
        for (int ct = 0; ct < 8; ++ct)
          acc[rt][ct] =
              __builtin_amdgcn_mfma_f32_16x16x32_bf16(af[rt], bfr[ct], acc[rt][ct], 0, 0, 0);
    }
    if (z < 8) {
#pragma unroll
      for (int rt = 0; rt < 2; ++rt)
#pragma unroll
        for (int ct = 0; ct < 8; ++ct) {
          int f = ct * 16 + l15;
#pragma unroll
          for (int i = 0; i < 4; ++i) {
            int m = row0 + rb + rt * 16 + quad * 4 + i;
            T[((size_t)m * 8 + z) * 128 + f] = f2bf(acc[rt][ct][i]);
          }
        }
    } else {
#pragma unroll
      for (int rt = 0; rt < 2; ++rt)
#pragma unroll
        for (int ct = 0; ct < 8; ++ct) {
          int f = ct * 16 + l15;
#pragma unroll
          for (int i = 0; i < 4; ++i) {
            int m = row0 + rb + rt * 16 + quad * 4 + i;
            t9f[(size_t)m * 128 + f] = acc[rt][ct][i];
          }
        }
    }
  }
}

// ---------------- layer 1 gather: l0_seg clone over the T table ----------------

__global__ __launch_bounds__(256) void l1_seg_kernel(
    const int* __restrict__ off2, const uint2* __restrict__ ep1,
    const unsigned short* __restrict__ T, const float* __restrict__ t9f,
    const float* __restrict__ bias1, unsigned short* __restrict__ x2b) {
  int lane = threadIdx.x & 63;
  int n = blockIdx.x * 4 + (threadIdx.x >> 6);
  if (n >= NP) return;
  const int g = lane >> 4;
  const int t = lane & 15;
  f32x2_t acc[4];
#pragma unroll
  for (int j = 0; j < 4; ++j) acc[j] = (f32x2_t){0.f, 0.f};

  if (n < NN) {
    int beg = off2[n * RRL];
    int end = off2[n * RRL + RRL];
    int i = beg + g;
    uint2 p0 = {0u, 0u}, p1 = {0u, 0u};
    if (i < end) p0 = ep1[i];
    if (i + 4 < end) p1 = ep1[i + 4];
    unsigned r0 = (p0.x & 0xFFFFFFu) * 8u + (p0.x >> 24);
    unsigned r1 = (p1.x & 0xFFFFFFu) * 8u + (p1.x >> 24);
    while (i < end) {
      uint2 q0 = {0u, 0u}, q1 = {0u, 0u};
      if (i + 8 < end) q0 = ep1[i + 8];
      if (i + 12 < end) q1 = ep1[i + 12];
      uint4 va = *(const uint4*)(T + (size_t)r0 * HH + t * 8);
      uint4 vb = *(const uint4*)(T + (size_t)r1 * HH + t * 8);
      acc8v(acc, va, __uint_as_float(p0.y));
      acc8v(acc, vb, __uint_as_float(p1.y));
      i += 8;
      p0 = q0;
      p1 = q1;
      r0 = (q0.x & 0xFFFFFFu) * 8u + (q0.x >> 24);
      r1 = (q1.x & 0xFFFFFFu) * 8u + (q1.x >> 24);
    }
  }
  float* af = (float*)acc;
#pragma unroll
  for (int j = 0; j < 8; ++j) {
    af[j] += __shfl_xor(af[j], 16, 64);
    af[j] += __shfl_xor(af[j], 32, 64);
  }
  if (g != 0) return;
  uint4 o = {0u, 0u, 0u, 0u};
  if (n < NN) {
    float4 l0v = ((const float4*)(t9f + (size_t)n * HH))[t * 2];
    float4 l1v = ((const float4*)(t9f + (size_t)n * HH))[t * 2 + 1];
    float4 b0v = ((const float4*)bias1)[t * 2];
    float4 b1v = ((const float4*)bias1)[t * 2 + 1];
    float e0 = fmaxf(af[0] + l0v.x + b0v.x, 0.f);
    float e1 = fmaxf(af[1] + l0v.y + b0v.y, 0.f);
    float e2 = fmaxf(af[2] + l0v.z + b0v.z, 0.f);
    float e3 = fmaxf(af[3] + l0v.w + b0v.w, 0.f);
    float e4 = fmaxf(af[4] + l1v.x + b1v.x, 0.f);
    float e5 = fmaxf(af[5] + l1v.y + b1v.y, 0.f);
    float e6 = fmaxf(af[6] + l1v.z + b1v.z, 0.f);
    float e7 = fmaxf(af[7] + l1v.w + b1v.w, 0.f);
    o.x = ((unsigned)f2bf(e1) << 16) | f2bf(e0);
    o.y = ((unsigned)f2bf(e3) << 16) | f2bf(e2);
    o.z = ((unsigned)f2bf(e5) << 16) | f2bf(e4);
    o.w = ((unsigned)f2bf(e7) << 16) | f2bf(e6);
  }
  *(uint4*)(x2b + (size_t)n * HH + t * 8) = o;
}

// ---------------- layer-2 transform: one pass over x2b, all 8 rels + self-loop ----------------

__global__ __launch_bounds__(256) void l2_trans_kernel(
    const unsigned short* __restrict__ x2b, const unsigned short* __restrict__ w2t,
    const unsigned short* __restrict__ loop2t, const float* __restrict__ bias2,
    unsigned short* __restrict__ trans2, float* __restrict__ out) {
  constexpr int LP = 136;
  __shared__ unsigned short Alds[128 * LP];
  __shared__ unsigned short Blds[9][16 * LP];
  const int row0 = blockIdx.x * 128;
  const int tid = threadIdx.x;

#pragma unroll
  for (int it = 0; it < 8; ++it) {
    int flat = tid + it * 256;
    int row = flat >> 4, c8 = flat & 15;
    *(uint4*)(&Alds[row * LP + c8 * 8]) =
        *(const uint4*)(x2b + ((size_t)(row0 + row)) * 128 + c8 * 8);
  }
  {
    int row = tid >> 4, c8 = tid & 15;
#pragma unroll
    for (int z = 0; z < 9; ++z) {
      const unsigned short* B = (z < 8) ? w2t + (size_t)z * CC * HH : loop2t;
      *(uint4*)(&Blds[z][row * LP + c8 * 8]) = *(const uint4*)(B + row * 128 + c8 * 8);
    }
  }
  __syncthreads();

  const int w = tid >> 6, lane = tid & 63;
  const int quad = lane >> 4, l15 = lane & 15;
  const int rb = w * 32;

  for (int z = 0; z < 9; ++z) {
    f32x4_t acc[2];
    acc[0] = (f32x4_t){0.f, 0.f, 0.f, 0.f};
    acc[1] = (f32x4_t){0.f, 0.f, 0.f, 0.f};
#pragma unroll
    for (int ks = 0; ks < 4; ++ks) {
      int ko = ks * 32 + quad * 8;
      bf16x8_t af0 = *(const bf16x8_t*)(&Alds[(rb + l15) * LP + ko]);
      bf16x8_t af1 = *(const bf16x8_t*)(&Alds[(rb + 16 + l15) * LP + ko]);
      bf16x8_t bfr = *(const bf16x8_t*)(&Blds[z][l15 * LP + ko]);
      acc[0] = __builtin_amdgcn_mfma_f32_16x16x32_bf16(af0, bfr, acc[0], 0, 0, 0);
      acc[1] = __builtin_amdgcn_mfma_f32_16x16x32_bf16(af1, bfr, acc[1], 0, 0, 0);
    }
    if (z < 8) {
      unsigned short* ob = trans2 + (size_t)z * NP * CC;
#pragma unroll
      for (int rt = 0; rt < 2; ++rt)
#pragma unroll
        for (int i = 0; i < 4; ++i) {
          int m = row0 + rb + rt * 16 + quad * 4 + i;
          ob[(size_t)m * CC + l15] = f2bf(acc[rt][i]);
        }
    } else {
      float bv = bias2[l15];
#pragma unroll
      for (int rt = 0; rt < 2; ++rt)
#pragma unroll
        for (int i = 0; i < 4; ++i) {
          int m = row0 + rb + rt * 16 + quad * 4 + i;
          if (m < NN) out[(size_t)m * CC + l15] = acc[rt][i] + bv;
        }
    }
  }
}

// ---------------- layer 2 gather: wave/dst, merged range, 8 slots x 8 lanes, 2x unroll ----------------

__global__ __launch_bounds__(256) void l2_seg_kernel(const int* __restrict__ off2,
                                                     const uint2* __restrict__ ep1,
                                                     const unsigned short* __restrict__ trans2,
                                                     float* __restrict__ outp) {
  int lane = threadIdx.x & 63;
  int n = blockIdx.x * 4 + (threadIdx.x >> 6);
  if (n >= NN) return;
  const int g = lane >> 3;
  const int t = lane & 7;
  float a0 = 0.f, a1 = 0.f;
  int beg = off2[n * RRL];
  int end = off2[n * RRL + RRL];
  int i = beg + g;
  uint2 p0 = {0u, 0u}, p1 = {0u, 0u};
  if (i < end) p0 = ep1[i];
  if (i + 8 < end) p1 = ep1[i + 8];
  while (i < end) {
    uint2 q0 = {0u, 0u}, q1 = {0u, 0u};
    if (i + 16 < end) q0 = ep1[i + 16];
    if (i + 24 < end) q1 = ep1[i + 24];
    unsigned s0 = p0.x & 0xFFFFFFu, z0 = p0.x >> 24;
    unsigned s1 = p1.x & 0xFFFFFFu, z1 = p1.x >> 24;
    unsigned int u0 =
        *(const unsigned int*)(trans2 + ((size_t)z0 * NP + s0) * CC + t * 2);
    unsigned int u1 =
        *(const unsigned int*)(trans2 + ((size_t)z1 * NP + s1) * CC + t * 2);
    float na = __uint_as_float(p0.y), nb = __uint_as_float(p1.y);
    a0 = fmaf(na, bflo(u0), a0);
    a1 = fmaf(na, bfhi(u0), a1);
    a0 = fmaf(nb, bflo(u1), a0);
    a1 = fmaf(nb, bfhi(u1), a1);
    i += 16;
    p0 = q0;
    p1 = q1;
  }
  a0 += __shfl_xor(a0, 8, 64);
  a0 += __shfl_xor(a0, 16, 64);
  a0 += __shfl_xor(a0, 32, 64);
  a1 += __shfl_xor(a1, 8, 64);
  a1 += __shfl_xor(a1, 16, 64);
  a1 += __shfl_xor(a1, 32, 64);
  if (g != 0) return;
  float2* o = (float2*)(outp + (size_t)n * CC) + t;
  float2 cv = *o;
  cv.x += a0;
  cv.y += a1;
  *o = cv;
}

// ---------------- launch ----------------

extern "C" void kernel_launch(void* const* d_in, const int* in_sizes, int n_in,
                              void* d_out, int out_size, void* d_ws, size_t ws_size,
                              hipStream_t stream) {
  const int* src = (const int*)d_in[0];
  const int* dst = (const int*)d_in[1];
  const int* h = (const int*)d_in[2];
  const int* r = (const int*)d_in[3];
  const float* norm = (const float*)d_in[4];
  const float* bases0 = (const float*)d_in[5];
  const float* wcomp0 = (const float*)d_in[6];
  const float* loop0 = (const float*)d_in[7];
  const float* bias0 = (const float*)d_in[8];
  const float* bases1 = (const float*)d_in[9];
  const float* wcomp1 = (const float*)d_in[10];
  const float* loop1 = (const float*)d_in[11];
  const float* bias1 = (const float*)d_in[12];
  const float* bases2 = (const float*)d_in[13];
  const float* wcomp2 = (const float*)d_in[14];
  const float* loop2 = (const float*)d_in[15];
  const float* bias2 = (const float*)d_in[16];
  float* out = (float*)d_out;

  char* p = (char*)d_ws;
  auto alloc = [&](size_t bytes) {
    char* q = p;
    p += (bytes + 255) & ~(size_t)255;
    return q;
  };
  unsigned short* x1b = (unsigned short*)alloc((size_t)NP * HH * 2);
  unsigned short* x2b = (unsigned short*)alloc((size_t)NP * HH * 2);
  unsigned short* trans2 = (unsigned short*)alloc((size_t)RRL * NP * CC * 2);
  unsigned short* w1big = (unsigned short*)alloc((size_t)HH * KBIG * 2);
  unsigned short* w2t = (unsigned short*)alloc((size_t)RRL * CC * HH * 2);
  unsigned short* loop2t = (unsigned short*)alloc((size_t)CC * HH * 2);
  float* t9f = (float*)alloc((size_t)NP * HH * 4);
  uint2* ep1 = (uint2*)alloc((size_t)EE * 8);
  uint2* epw = (uint2*)alloc((size_t)EE * 8);
  uint4* tmpR = (uint4*)alloc((size_t)NC * CAP * 16);
  int* off2 = (int*)alloc((size_t)(NT + 1) * 4);
  int* tmpCur = (int*)alloc(2048);  // 512 ints >= NC=391
  // BIG: w0b [NN][8][128] bf16 during layer 0, then reused as T [NP][8][128] bf16
  unsigned short* BIG = (unsigned short*)alloc((size_t)RRL * NP * HH * 2);

  // ---- fused front: edge partition (LDS-only atomics) + weight prep ----
  hipMemsetAsync(tmpCur, 0, 2048, stream);
  front_kernel<<<FRONT_BLOCKS, 256, 0, stream>>>(
      r, dst, src, norm, tmpCur, tmpR, bases0, wcomp0, BIG, wcomp1, bases1, loop1,
      wcomp2, bases2, loop2, w1big, w2t, loop2t);

  // ---- per-bucket local counting sort: off2 + ep1 + epw in one kernel ----
  placeB_kernel<<<NC, 256, 0, stream>>>(tmpCur, tmpR, h, off2, ep1, epw);

  // ---- layer 0 ----
  l0_seg_kernel<<<NP / 4, 256, 0, stream>>>(h, off2, epw, BIG, loop0, bias0, x1b);

  // ---- layer 1: transform-then-gather (T overwrites w0b in BIG) ----
  t1_gemm_kernel<<<NP / 128, 256, 0, stream>>>(x1b, w1big, BIG, t9f);
  l1_seg_kernel<<<NP / 4, 256, 0, stream>>>(off2, ep1, BIG, t9f, bias1, x2b);

  // ---- layer 2 ----
  l2_trans_kernel<<<NP / 128, 256, 0, stream>>>(x2b, w2t, loop2t, bias2, trans2, out);
  l2_seg_kernel<<<(NN + 3) / 4, 256, 0, stream>>>(off2, ep1, trans2, out);
}

// Round 15
// 400.307 us; speedup vs baseline: 1.1884x; 1.0184x over previous
//
#include <hip/hip_runtime.h>

#define NN 50000
#define NP 50048            // padded rows (multiple of 128)
#define HH 128
#define CC 16
#define RRL 8
#define BB 4
#define EE 800000
#define NT (RRL * NN)       // 400000 (dst,rel) buckets, key = dst*8+rel
#define KBIG 1152           // 8*128 (relations) + 128 (self-loop)
#define W0B_BLOCKS ((NN * 8 + 255) / 256)               // 1563 (16 floats/thread)
#define COMPOSE_THREADS (HH * KBIG + RRL * CC * HH + CC * HH)
#define COMPOSE_BLOCKS ((COMPOSE_THREADS + 255) / 256)  // 648
// coarse bucket = dst>>7 (128 dst = 1024 keys per bucket)
#define NC 391
#define KPB 1024            // keys per coarse bucket
#define CAP 2560            // per-bucket tmp capacity (mean 2046, sigma~45)
#define CHUNK_E 4096
#define EPT (CHUNK_E / 256) // 16 edges per thread
#define PA_BLOCKS ((EE + CHUNK_E - 1) / CHUNK_E)        // 196
#define FRONT_BLOCKS (PA_BLOCKS + W0B_BLOCKS + COMPOSE_BLOCKS)

typedef short bf16x8_t __attribute__((ext_vector_type(8)));
typedef float f32x4_t __attribute__((ext_vector_type(4)));
typedef float f32x2_t __attribute__((ext_vector_type(2)));

__device__ __forceinline__ unsigned short f2bf(float f) {
  unsigned int x = __float_as_uint(f);
  unsigned int r = x + 0x7fffu + ((x >> 16) & 1u);
  return (unsigned short)(r >> 16);
}
__device__ __forceinline__ float bflo(unsigned int u) { return __uint_as_float(u << 16); }
__device__ __forceinline__ float bfhi(unsigned int u) {
  return __uint_as_float(u & 0xffff0000u);
}
// packed-f32 accumulate: 4x v_pk_fma_f32 instead of 8 scalar v_fma (contract=fast)
__device__ __forceinline__ void acc8v(f32x2_t* a, uint4 v, float nrm) {
  f32x2_t nn = {nrm, nrm};
  f32x2_t u0 = {bflo(v.x), bfhi(v.x)};
  f32x2_t u1 = {bflo(v.y), bfhi(v.y)};
  f32x2_t u2 = {bflo(v.z), bfhi(v.z)};
  f32x2_t u3 = {bflo(v.w), bfhi(v.w)};
  a[0] += nn * u0;
  a[1] += nn * u1;
  a[2] += nn * u2;
  a[3] += nn * u3;
}

// ---------------- fused front kernel ----------------
// blocks [0, PA_BLOCKS): edge partition into coarse buckets — LDS-only atomics,
//   one 8-B record {src | z<<17 | (dst&127)<<20, norm} per edge (src<2^17, z<8).
// blocks [PA_BLOCKS, +W0B_BLOCKS): w0b table build (HBM-BW-bound)
// blocks [.., +COMPOSE_BLOCKS): small composed weights

__global__ __launch_bounds__(256) void front_kernel(
    const int* __restrict__ r, const int* __restrict__ dst, const int* __restrict__ src,
    const float* __restrict__ norm, int* __restrict__ tmpCur, uint2* __restrict__ tmpR,
    const float* __restrict__ bases0, const float* __restrict__ wcomp0,
    unsigned short* __restrict__ w0b, const float* __restrict__ wcomp1,
    const float* __restrict__ bases1, const float* __restrict__ loop1,
    const float* __restrict__ wcomp2, const float* __restrict__ bases2,
    const float* __restrict__ loop2, unsigned short* __restrict__ w1big,
    unsigned short* __restrict__ w2t, unsigned short* __restrict__ loop2t) {
  __shared__ int hist[NC];
  __shared__ int run[NC];
  int tid = threadIdx.x;
  if (blockIdx.x < PA_BLOCKS) {
    int base = blockIdx.x * CHUNK_E;
    for (int i = tid; i < NC; i += 256) hist[i] = 0;
    __syncthreads();
    int dcache[EPT];
#pragma unroll
    for (int j = 0; j < EPT; ++j) {
      int e = base + tid + j * 256;
      dcache[j] = (e < EE) ? dst[e] : -1;
      if (e < EE) atomicAdd(&hist[dcache[j] >> 7], 1);
    }
    __syncthreads();
    for (int i = tid; i < NC; i += 256)
      if (hist[i] > 0) run[i] = i * CAP + atomicAdd(&tmpCur[i], hist[i]);
    __syncthreads();
#pragma unroll
    for (int j = 0; j < EPT; ++j) {
      int e = base + tid + j * 256;
      if (e < EE) {
        int d = dcache[j], z = r[e];
        int c = d >> 7;
        int pos = atomicAdd(&run[c], 1);
        uint2 rec;
        rec.x = (unsigned)src[e] | ((unsigned)z << 17) | ((unsigned)(d & 127) << 20);
        rec.y = __float_as_uint(norm[e]);
        tmpR[pos] = rec;
      }
    }
    return;
  }
  int bx = blockIdx.x - PA_BLOCKS;
  if (bx < W0B_BLOCKS) {
    // ---- w0b table [m][z][f]: 16 floats/thread -> 16 loads in flight ----
    int idx = bx * 256 + tid;  // m*8 + c16
    int m = idx >> 3, c16 = idx & 7;
    if (m >= NN) return;
    float4 a[BB][4];
#pragma unroll
    for (int b = 0; b < BB; ++b) {
      const float4* sp = (const float4*)(bases0 + ((size_t)b * NN + m) * HH + c16 * 16);
      a[b][0] = sp[0];
      a[b][1] = sp[1];
      a[b][2] = sp[2];
      a[b][3] = sp[3];
    }
    uint4* orow = (uint4*)w0b + (size_t)m * 128 + c16 * 2;
#pragma unroll
    for (int z = 0; z < RRL; ++z) {
      float c0 = wcomp0[z * BB + 0], c1 = wcomp0[z * BB + 1];
      float c2 = wcomp0[z * BB + 2], c3 = wcomp0[z * BB + 3];
      float e[16];
#pragma unroll
      for (int q = 0; q < 4; ++q) {
        e[q * 4 + 0] = c0 * a[0][q].x + c1 * a[1][q].x + c2 * a[2][q].x + c3 * a[3][q].x;
        e[q * 4 + 1] = c0 * a[0][q].y + c1 * a[1][q].y + c2 * a[2][q].y + c3 * a[3][q].y;
        e[q * 4 + 2] = c0 * a[0][q].z + c1 * a[1][q].z + c2 * a[2][q].z + c3 * a[3][q].z;
        e[q * 4 + 3] = c0 * a[0][q].w + c1 * a[1][q].w + c2 * a[2][q].w + c3 * a[3][q].w;
      }
      uint4 pk0, pk1;
      pk0.x = ((unsigned)f2bf(e[1]) << 16) | f2bf(e[0]);
      pk0.y = ((unsigned)f2bf(e[3]) << 16) | f2bf(e[2]);
      pk0.z = ((unsigned)f2bf(e[5]) << 16) | f2bf(e[4]);
      pk0.w = ((unsigned)f2bf(e[7]) << 16) | f2bf(e[6]);
      pk1.x = ((unsigned)f2bf(e[9]) << 16) | f2bf(e[8]);
      pk1.y = ((unsigned)f2bf(e[11]) << 16) | f2bf(e[10]);
      pk1.z = ((unsigned)f2bf(e[13]) << 16) | f2bf(e[12]);
      pk1.w = ((unsigned)f2bf(e[15]) << 16) | f2bf(e[14]);
      orow[z * 16] = pk0;
      orow[z * 16 + 1] = pk1;
    }
    return;
  }
  // ---- composed small weights ----
  int idx = (bx - W0B_BLOCKS) * 256 + tid;
  if (idx < HH * KBIG) {  // w1big[n][k]
    int n = idx / KBIG, k = idx - n * KBIG;
    float a;
    if (k < 1024) {
      int z = k >> 7, kk = k & 127;
      a = 0.f;
#pragma unroll
      for (int b = 0; b < BB; ++b)
        a += wcomp1[z * BB + b] * bases1[((size_t)b * HH + kk) * HH + n];
    } else {
      int kk = k - 1024;
      a = loop1[kk * HH + n];
    }
    w1big[idx] = f2bf(a);
    return;
  }
  int j = idx - HH * KBIG;
  if (j < RRL * CC * HH) {  // w2t[z][n][k]
    int z = j >> 11;
    int rem = j & 2047;
    int n = rem >> 7, k = rem & 127;
    float a = 0.f;
#pragma unroll
    for (int b = 0; b < BB; ++b)
      a += wcomp2[z * BB + b] * bases2[((size_t)b * HH + k) * CC + n];
    w2t[j] = f2bf(a);
    return;
  }
  j -= RRL * CC * HH;
  if (j < CC * HH) {  // loop2t[n][k]
    int n = j >> 7, k = j & 127;
    loop2t[j] = f2bf(loop2[k * CC + n]);
  }
}

// ---------------- placeB: per-bucket local counting sort ----------------
// One block per coarse bucket (1024 keys, ~2046 records). lk = (packed>>17)&1023
// == (dst&127)*8 + z by bit layout. Rebuilds ep1's src|z<<24 payload and
// resolves epw = (h[src]*8+z, norm) here (h is L2-resident).

__global__ __launch_bounds__(256) void placeB_kernel(const int* __restrict__ tmpCur,
                                                     const uint2* __restrict__ tmpR,
                                                     const int* __restrict__ h,
                                                     int* __restrict__ off2,
                                                     uint2* __restrict__ ep1,
                                                     uint2* __restrict__ epw) {
  __shared__ int lh[KPB];
  __shared__ int sums[256];
  const int c = blockIdx.x;
  const int tid = threadIdx.x;
  const int cnt = tmpCur[c];
  const int base = c * CAP;
  // coarse base = sum of tmpCur[0..c-1]
  int partial = 0;
  for (int j = tid; j < c; j += 256) partial += tmpCur[j];
  sums[tid] = partial;
  __syncthreads();
  for (int o = 1; o < 256; o <<= 1) {
    int t = (tid >= o) ? sums[tid - o] : 0;
    __syncthreads();
    sums[tid] += t;
    __syncthreads();
  }
  const int cbase = sums[255];
  // local histogram
  for (int j = tid; j < KPB; j += 256) lh[j] = 0;
  __syncthreads();
  for (int i = tid; i < cnt; i += 256)
    atomicAdd(&lh[(tmpR[base + i].x >> 17) & 1023], 1);
  __syncthreads();
  // exclusive prefix over lh (4 per thread)
  int v0 = lh[tid * 4], v1 = lh[tid * 4 + 1], v2 = lh[tid * 4 + 2], v3 = lh[tid * 4 + 3];
  int s = v0 + v1 + v2 + v3;
  sums[tid] = s;
  __syncthreads();
  for (int o = 1; o < 256; o <<= 1) {
    int t = (tid >= o) ? sums[tid - o] : 0;
    __syncthreads();
    sums[tid] += t;
    __syncthreads();
  }
  int run = sums[tid] - s;
  lh[tid * 4] = run;
  lh[tid * 4 + 1] = run + v0;
  lh[tid * 4 + 2] = run + v0 + v1;
  lh[tid * 4 + 3] = run + v0 + v1 + v2;
  // write off2 slice
  const int key0 = c * KPB;
#pragma unroll
  for (int j = 0; j < 4; ++j) {
    int key = key0 + tid * 4 + j;
    if (key < NT) off2[key] = cbase + lh[tid * 4 + j];
  }
  if (c == 0 && tid == 0) off2[NT] = EE;
  __syncthreads();
  // place (lh becomes the cursor)
  for (int i = tid; i < cnt; i += 256) {
    uint2 rec = tmpR[base + i];
    int lk = (rec.x >> 17) & 1023;
    int pos = cbase + atomicAdd(&lh[lk], 1);
    unsigned sv = rec.x & 0x1FFFFu, z = (rec.x >> 17) & 7u;
    ep1[pos] = (uint2){sv | (z << 24), rec.y};
    epw[pos] = (uint2){(unsigned)h[sv] * 8u + z, rec.y};
  }
}

// ---------------- layer 0: wave/dst, merged range, 4 slots x 16 lanes, 2-deep ----------------
// epw carries the pre-resolved w0b row (h[src]*8+z) + norm (round-10 proven form).

__global__ __launch_bounds__(256) void l0_seg_kernel(
    const int* __restrict__ h, const int* __restrict__ off2, const uint2* __restrict__ epw,
    const unsigned short* __restrict__ w0b, const float* __restrict__ loop0,
    const float* __restrict__ bias0, unsigned short* __restrict__ x1b) {
  int lane = threadIdx.x & 63;
  int n = blockIdx.x * 4 + (threadIdx.x >> 6);
  if (n >= NP) return;
  const int g = lane >> 4;
  const int t = lane & 15;
  f32x2_t acc[4];
#pragma unroll
  for (int j = 0; j < 4; ++j) acc[j] = (f32x2_t){0.f, 0.f};

  if (n < NN) {
    int beg = off2[n * RRL];
    int end = off2[n * RRL + RRL];
    int i = beg + g;
    uint2 p0 = {0u, 0u}, p1 = {0u, 0u};
    if (i < end) p0 = epw[i];
    if (i + 4 < end) p1 = epw[i + 4];
    while (i < end) {
      uint2 q0 = {0u, 0u}, q1 = {0u, 0u};
      if (i + 8 < end) q0 = epw[i + 8];
      if (i + 12 < end) q1 = epw[i + 12];
      uint4 va = *(const uint4*)(w0b + (size_t)p0.x * HH + t * 8);
      uint4 vb = *(const uint4*)(w0b + (size_t)p1.x * HH + t * 8);
      acc8v(acc, va, __uint_as_float(p0.y));
      acc8v(acc, vb, __uint_as_float(p1.y));
      i += 8;
      p0 = q0;
      p1 = q1;
    }
  }
  float* af = (float*)acc;
#pragma unroll
  for (int j = 0; j < 8; ++j) {
    af[j] += __shfl_xor(af[j], 16, 64);
    af[j] += __shfl_xor(af[j], 32, 64);
  }
  if (g != 0) return;
  uint4 o = {0u, 0u, 0u, 0u};
  if (n < NN) {
    int hn = h[n];
    float4 l0v = ((const float4*)(loop0 + (size_t)hn * HH))[t * 2];
    float4 l1v = ((const float4*)(loop0 + (size_t)hn * HH))[t * 2 + 1];
    float4 b0v = ((const float4*)bias0)[t * 2];
    float4 b1v = ((const float4*)bias0)[t * 2 + 1];
    float e0 = fmaxf(af[0] + l0v.x + b0v.x, 0.f);
    float e1 = fmaxf(af[1] + l0v.y + b0v.y, 0.f);
    float e2 = fmaxf(af[2] + l0v.z + b0v.z, 0.f);
    float e3 = fmaxf(af[3] + l0v.w + b0v.w, 0.f);
    float e4 = fmaxf(af[4] + l1v.x + b1v.x, 0.f);
    float e5 = fmaxf(af[5] + l1v.y + b1v.y, 0.f);
    float e6 = fmaxf(af[6] + l1v.z + b1v.z, 0.f);
    float e7 = fmaxf(af[7] + l1v.w + b1v.w, 0.f);
    o.x = ((unsigned)f2bf(e1) << 16) | f2bf(e0);
    o.y = ((unsigned)f2bf(e3) << 16) | f2bf(e2);
    o.z = ((unsigned)f2bf(e5) << 16) | f2bf(e4);
    o.w = ((unsigned)f2bf(e7) << 16) | f2bf(e6);
  }
  *(uint4*)(x1b + (size_t)n * HH + t * 8) = o;
}

// ---------------- layer 1 transform GEMM: T[m][z][f] = x1b @ W_z^T, t9f = x1b @ loop1^T ----

__global__ __launch_bounds__(256) void t1_gemm_kernel(const unsigned short* __restrict__ x1b,
                                                      const unsigned short* __restrict__ w1big,
                                                      unsigned short* __restrict__ T,
                                                      float* __restrict__ t9f) {
  constexpr int LP = 136;
  __shared__ unsigned short Alds[128 * LP];
  __shared__ unsigned short Blds[128 * LP];
  const int row0 = blockIdx.x * 128;
  const int tid = threadIdx.x;
  const int w = tid >> 6, lane = tid & 63;
  const int quad = lane >> 4, l15 = lane & 15;
  const int rb = w * 32;

#pragma unroll
  for (int it = 0; it < 8; ++it) {
    int flat = tid + it * 256;
    int row = flat >> 4, c8 = flat & 15;
    *(uint4*)(&Alds[row * LP + c8 * 8]) =
        *(const uint4*)(x1b + (size_t)(row0 + row) * 128 + c8 * 8);
  }

  for (int z = 0; z < 9; ++z) {
    __syncthreads();  // prior readers of Blds done (covers A load on z=0)
#pragma unroll
    for (int it = 0; it < 8; ++it) {
      int flat = tid + it * 256;
      int row = flat >> 4, c8 = flat & 15;
      *(uint4*)(&Blds[row * LP + c8 * 8]) =
          *(const uint4*)(w1big + (size_t)row * KBIG + z * 128 + c8 * 8);
    }
    __syncthreads();
    f32x4_t acc[2][8];
#pragma unroll
    for (int rt = 0; rt < 2; ++rt)
#pragma unroll
      for (int ct = 0; ct < 8; ++ct) acc[rt][ct] = (f32x4_t){0.f, 0.f, 0.f, 0.f};
#pragma unroll
    for (int ks = 0; ks < 4; ++ks) {
      int ko = ks * 32 + quad * 8;
      bf16x8_t af[2], bfr[8];
#pragma unroll
      for (int rt = 0; rt < 2; ++rt)
        af[rt] = *(const bf16x8_t*)(&Alds[(rb + rt * 16 + l15) * LP + ko]);
#pragma unroll
      for (int ct = 0; ct < 8; ++ct)
        bfr[ct] = *(const bf16x8_t*)(&Blds[(ct * 16 + l15) * LP + ko]);
#pragma unroll
      for (int rt = 0; rt < 2; ++rt)
#pragma unroll
        for (int ct = 0; ct < 8; ++ct)
          acc[rt][ct] =
              __builtin_amdgcn_mfma_f32_16x16x32_bf16(af[rt], bfr[ct], acc[rt][ct], 0, 0, 0);
    }
    if (z < 8) {
#pragma unroll
      for (int rt = 0; rt < 2; ++rt)
#pragma unroll
        for (int ct = 0; ct < 8; ++ct) {
          int f = ct * 16 + l15;
#pragma unroll
          for (int i = 0; i < 4; ++i) {
            int m = row0 + rb + rt * 16 + quad * 4 + i;
            T[((size_t)m * 8 + z) * 128 + f] = f2bf(acc[rt][ct][i]);
          }
        }
    } else {
#pragma unroll
      for (int rt = 0; rt < 2; ++rt)
#pragma unroll
        for (int ct = 0; ct < 8; ++ct) {
          int f = ct * 16 + l15;
#pragma unroll
          for (int i = 0; i < 4; ++i) {
            int m = row0 + rb + rt * 16 + quad * 4 + i;
            t9f[(size_t)m * 128 + f] = acc[rt][ct][i];
          }
        }
    }
  }
}

// ---------------- layer 1 gather: l0_seg clone over the T table ----------------

__global__ __launch_bounds__(256) void l1_seg_kernel(
    const int* __restrict__ off2, const uint2* __restrict__ ep1,
    const unsigned short* __restrict__ T, const float* __restrict__ t9f,
    const float* __restrict__ bias1, unsigned short* __restrict__ x2b) {
  int lane = threadIdx.x & 63;
  int n = blockIdx.x * 4 + (threadIdx.x >> 6);
  if (n >= NP) return;
  const int g = lane >> 4;
  const int t = lane & 15;
  f32x2_t acc[4];
#pragma unroll
  for (int j = 0; j < 4; ++j) acc[j] = (f32x2_t){0.f, 0.f};

  if (n < NN) {
    int beg = off2[n * RRL];
    int end = off2[n * RRL + RRL];
    int i = beg + g;
    uint2 p0 = {0u, 0u}, p1 = {0u, 0u};
    if (i < end) p0 = ep1[i];
    if (i + 4 < end) p1 = ep1[i + 4];
    unsigned r0 = (p0.x & 0xFFFFFFu) * 8u + (p0.x >> 24);
    unsigned r1 = (p1.x & 0xFFFFFFu) * 8u + (p1.x >> 24);
    while (i < end) {
      uint2 q0 = {0u, 0u}, q1 = {0u, 0u};
      if (i + 8 < end) q0 = ep1[i + 8];
      if (i + 12 < end) q1 = ep1[i + 12];
      uint4 va = *(const uint4*)(T + (size_t)r0 * HH + t * 8);
      uint4 vb = *(const uint4*)(T + (size_t)r1 * HH + t * 8);
      acc8v(acc, va, __uint_as_float(p0.y));
      acc8v(acc, vb, __uint_as_float(p1.y));
      i += 8;
      p0 = q0;
      p1 = q1;
      r0 = (q0.x & 0xFFFFFFu) * 8u + (q0.x >> 24);
      r1 = (q1.x & 0xFFFFFFu) * 8u + (q1.x >> 24);
    }
  }
  float* af = (float*)acc;
#pragma unroll
  for (int j = 0; j < 8; ++j) {
    af[j] += __shfl_xor(af[j], 16, 64);
    af[j] += __shfl_xor(af[j], 32, 64);
  }
  if (g != 0) return;
  uint4 o = {0u, 0u, 0u, 0u};
  if (n < NN) {
    float4 l0v = ((const float4*)(t9f + (size_t)n * HH))[t * 2];
    float4 l1v = ((const float4*)(t9f + (size_t)n * HH))[t * 2 + 1];
    float4 b0v = ((const float4*)bias1)[t * 2];
    float4 b1v = ((const float4*)bias1)[t * 2 + 1];
    float e0 = fmaxf(af[0] + l0v.x + b0v.x, 0.f);
    float e1 = fmaxf(af[1] + l0v.y + b0v.y, 0.f);
    float e2 = fmaxf(af[2] + l0v.z + b0v.z, 0.f);
    float e3 = fmaxf(af[3] + l0v.w + b0v.w, 0.f);
    float e4 = fmaxf(af[4] + l1v.x + b1v.x, 0.f);
    float e5 = fmaxf(af[5] + l1v.y + b1v.y, 0.f);
    float e6 = fmaxf(af[6] + l1v.z + b1v.z, 0.f);
    float e7 = fmaxf(af[7] + l1v.w + b1v.w, 0.f);
    o.x = ((unsigned)f2bf(e1) << 16) | f2bf(e0);
    o.y = ((unsigned)f2bf(e3) << 16) | f2bf(e2);
    o.z = ((unsigned)f2bf(e5) << 16) | f2bf(e4);
    o.w = ((unsigned)f2bf(e7) << 16) | f2bf(e6);
  }
  *(uint4*)(x2b + (size_t)n * HH + t * 8) = o;
}

// ---------------- layer-2 transform: one pass over x2b, all 8 rels + self-loop ----------------

__global__ __launch_bounds__(256) void l2_trans_kernel(
    const unsigned short* __restrict__ x2b, const unsigned short* __restrict__ w2t,
    const unsigned short* __restrict__ loop2t, const float* __restrict__ bias2,
    unsigned short* __restrict__ trans2, float* __restrict__ out) {
  constexpr int LP = 136;
  __shared__ unsigned short Alds[128 * LP];
  __shared__ unsigned short Blds[9][16 * LP];
  const int row0 = blockIdx.x * 128;
  const int tid = threadIdx.x;

#pragma unroll
  for (int it = 0; it < 8; ++it) {
    int flat = tid + it * 256;
    int row = flat >> 4, c8 = flat & 15;
    *(uint4*)(&Alds[row * LP + c8 * 8]) =
        *(const uint4*)(x2b + ((size_t)(row0 + row)) * 128 + c8 * 8);
  }
  {
    int row = tid >> 4, c8 = tid & 15;
#pragma unroll
    for (int z = 0; z < 9; ++z) {
      const unsigned short* B = (z < 8) ? w2t + (size_t)z * CC * HH : loop2t;
      *(uint4*)(&Blds[z][row * LP + c8 * 8]) = *(const uint4*)(B + row * 128 + c8 * 8);
    }
  }
  __syncthreads();

  const int w = tid >> 6, lane = tid & 63;
  const int quad = lane >> 4, l15 = lane & 15;
  const int rb = w * 32;

  for (int z = 0; z < 9; ++z) {
    f32x4_t acc[2];
    acc[0] = (f32x4_t){0.f, 0.f, 0.f, 0.f};
    acc[1] = (f32x4_t){0.f, 0.f, 0.f, 0.f};
#pragma unroll
    for (int ks = 0; ks < 4; ++ks) {
      int ko = ks * 32 + quad * 8;
      bf16x8_t af0 = *(const bf16x8_t*)(&Alds[(rb + l15) * LP + ko]);
      bf16x8_t af1 = *(const bf16x8_t*)(&Alds[(rb + 16 + l15) * LP + ko]);
      bf16x8_t bfr = *(const bf16x8_t*)(&Blds[z][l15 * LP + ko]);
      acc[0] = __builtin_amdgcn_mfma_f32_16x16x32_bf16(af0, bfr, acc[0], 0, 0, 0);
      acc[1] = __builtin_amdgcn_mfma_f32_16x16x32_bf16(af1, bfr, acc[1], 0, 0, 0);
    }
    if (z < 8) {
      unsigned short* ob = trans2 + (size_t)z * NP * CC;
#pragma unroll
      for (int rt = 0; rt < 2; ++rt)
#pragma unroll
        for (int i = 0; i < 4; ++i) {
          int m = row0 + rb + rt * 16 + quad * 4 + i;
          ob[(size_t)m * CC + l15] = f2bf(acc[rt][i]);
        }
    } else {
      float bv = bias2[l15];
#pragma unroll
      for (int rt = 0; rt < 2; ++rt)
#pragma unroll
        for (int i = 0; i < 4; ++i) {
          int m = row0 + rb + rt * 16 + quad * 4 + i;
          if (m < NN) out[(size_t)m * CC + l15] = acc[rt][i] + bv;
        }
    }
  }
}

// ---------------- layer 2 gather: wave/dst, merged range, 8 slots x 8 lanes, 2x unroll ----------------

__global__ __launch_bounds__(256) void l2_seg_kernel(const int* __restrict__ off2,
                                                     const uint2* __restrict__ ep1,
                                                     const unsigned short* __restrict__ trans2,
                                                     float* __restrict__ outp) {
  int lane = threadIdx.x & 63;
  int n = blockIdx.x * 4 + (threadIdx.x >> 6);
  if (n >= NN) return;
  const int g = lane >> 3;
  const int t = lane & 7;
  float a0 = 0.f, a1 = 0.f;
  int beg = off2[n * RRL];
  int end = off2[n * RRL + RRL];
  int i = beg + g;
  uint2 p0 = {0u, 0u}, p1 = {0u, 0u};
  if (i < end) p0 = ep1[i];
  if (i + 8 < end) p1 = ep1[i + 8];
  while (i < end) {
    uint2 q0 = {0u, 0u}, q1 = {0u, 0u};
    if (i + 16 < end) q0 = ep1[i + 16];
    if (i + 24 < end) q1 = ep1[i + 24];
    unsigned s0 = p0.x & 0xFFFFFFu, z0 = p0.x >> 24;
    unsigned s1 = p1.x & 0xFFFFFFu, z1 = p1.x >> 24;
    unsigned int u0 =
        *(const unsigned int*)(trans2 + ((size_t)z0 * NP + s0) * CC + t * 2);
    unsigned int u1 =
        *(const unsigned int*)(trans2 + ((size_t)z1 * NP + s1) * CC + t * 2);
    float na = __uint_as_float(p0.y), nb = __uint_as_float(p1.y);
    a0 = fmaf(na, bflo(u0), a0);
    a1 = fmaf(na, bfhi(u0), a1);
    a0 = fmaf(nb, bflo(u1), a0);
    a1 = fmaf(nb, bfhi(u1), a1);
    i += 16;
    p0 = q0;
    p1 = q1;
  }
  a0 += __shfl_xor(a0, 8, 64);
  a0 += __shfl_xor(a0, 16, 64);
  a0 += __shfl_xor(a0, 32, 64);
  a1 += __shfl_xor(a1, 8, 64);
  a1 += __shfl_xor(a1, 16, 64);
  a1 += __shfl_xor(a1, 32, 64);
  if (g != 0) return;
  float2* o = (float2*)(outp + (size_t)n * CC) + t;
  float2 cv = *o;
  cv.x += a0;
  cv.y += a1;
  *o = cv;
}

// ---------------- launch ----------------

extern "C" void kernel_launch(void* const* d_in, const int* in_sizes, int n_in,
                              void* d_out, int out_size, void* d_ws, size_t ws_size,
                              hipStream_t stream) {
  const int* src = (const int*)d_in[0];
  const int* dst = (const int*)d_in[1];
  const int* h = (const int*)d_in[2];
  const int* r = (const int*)d_in[3];
  const float* norm = (const float*)d_in[4];
  const float* bases0 = (const float*)d_in[5];
  const float* wcomp0 = (const float*)d_in[6];
  const float* loop0 = (const float*)d_in[7];
  const float* bias0 = (const float*)d_in[8];
  const float* bases1 = (const float*)d_in[9];
  const float* wcomp1 = (const float*)d_in[10];
  const float* loop1 = (const float*)d_in[11];
  const float* bias1 = (const float*)d_in[12];
  const float* bases2 = (const float*)d_in[13];
  const float* wcomp2 = (const float*)d_in[14];
  const float* loop2 = (const float*)d_in[15];
  const float* bias2 = (const float*)d_in[16];
  float* out = (float*)d_out;

  char* p = (char*)d_ws;
  auto alloc = [&](size_t bytes) {
    char* q = p;
    p += (bytes + 255) & ~(size_t)255;
    return q;
  };
  unsigned short* x1b = (unsigned short*)alloc((size_t)NP * HH * 2);
  unsigned short* x2b = (unsigned short*)alloc((size_t)NP * HH * 2);
  unsigned short* trans2 = (unsigned short*)alloc((size_t)RRL * NP * CC * 2);
  unsigned short* w1big = (unsigned short*)alloc((size_t)HH * KBIG * 2);
  unsigned short* w2t = (unsigned short*)alloc((size_t)RRL * CC * HH * 2);
  unsigned short* loop2t = (unsigned short*)alloc((size_t)CC * HH * 2);
  float* t9f = (float*)alloc((size_t)NP * HH * 4);
  uint2* ep1 = (uint2*)alloc((size_t)EE * 8);
  uint2* epw = (uint2*)alloc((size_t)EE * 8);
  uint2* tmpR = (uint2*)alloc((size_t)NC * CAP * 8);
  int* off2 = (int*)alloc((size_t)(NT + 1) * 4);
  int* tmpCur = (int*)alloc(2048);  // 512 ints >= NC=391
  // BIG: w0b [NN][8][128] bf16 during layer 0, then reused as T [NP][8][128] bf16
  unsigned short* BIG = (unsigned short*)alloc((size_t)RRL * NP * HH * 2);

  // ---- fused front: edge partition (LDS-only atomics) + weight prep ----
  hipMemsetAsync(tmpCur, 0, 2048, stream);
  front_kernel<<<FRONT_BLOCKS, 256, 0, stream>>>(
      r, dst, src, norm, tmpCur, tmpR, bases0, wcomp0, BIG, wcomp1, bases1, loop1,
      wcomp2, bases2, loop2, w1big, w2t, loop2t);

  // ---- per-bucket local counting sort: off2 + ep1 + epw in one kernel ----
  placeB_kernel<<<NC, 256, 0, stream>>>(tmpCur, tmpR, h, off2, ep1, epw);

  // ---- layer 0 ----
  l0_seg_kernel<<<NP / 4, 256, 0, stream>>>(h, off2, epw, BIG, loop0, bias0, x1b);

  // ---- layer 1: transform-then-gather (T overwrites w0b in BIG) ----
  t1_gemm_kernel<<<NP / 128, 256, 0, stream>>>(x1b, w1big, BIG, t9f);
  l1_seg_kernel<<<NP / 4, 256, 0, stream>>>(off2, ep1, BIG, t9f, bias1, x2b);

  // ---- layer 2 ----
  l2_trans_kernel<<<NP / 128, 256, 0, stream>>>(x2b, w2t, loop2t, bias2, trans2, out);
  l2_seg_kernel<<<(NN + 3) / 4, 256, 0, stream>>>(off2, ep1, trans2, out);
}

// Round 16
// 395.313 us; speedup vs baseline: 1.2034x; 1.0126x over previous
//
#include <hip/hip_runtime.h>

#define NN 50000
#define NP 50048            // padded rows (multiple of 128)
#define HH 128
#define CC 16
#define RRL 8
#define BB 4
#define EE 800000
#define NT (RRL * NN)       // 400000 (dst,rel) buckets, key = dst*8+rel
#define KBIG 1152           // 8*128 (relations) + 128 (self-loop)
#define W0B_BLOCKS ((NN * 8 + 255) / 256)               // 1563 (16 floats/thread)
#define COMPOSE_THREADS (HH * KBIG + RRL * CC * HH + CC * HH)
#define COMPOSE_BLOCKS ((COMPOSE_THREADS + 255) / 256)  // 648
// coarse bucket = dst>>7 (128 dst = 1024 keys per bucket)
#define NC 391
#define KPB 1024            // keys per coarse bucket
#define CAP 2560            // per-bucket tmp capacity (mean 2046, sigma~45)
#define CHUNK_E 4096
#define EPT (CHUNK_E / 256) // 16 edges per thread
#define PA_BLOCKS ((EE + CHUNK_E - 1) / CHUNK_E)        // 196
#define FRONT_BLOCKS (PA_BLOCKS + W0B_BLOCKS + COMPOSE_BLOCKS)

typedef short bf16x8_t __attribute__((ext_vector_type(8)));
typedef float f32x4_t __attribute__((ext_vector_type(4)));
typedef float f32x2_t __attribute__((ext_vector_type(2)));

__device__ __forceinline__ unsigned short f2bf(float f) {
  unsigned int x = __float_as_uint(f);
  unsigned int r = x + 0x7fffu + ((x >> 16) & 1u);
  return (unsigned short)(r >> 16);
}
__device__ __forceinline__ float bflo(unsigned int u) { return __uint_as_float(u << 16); }
__device__ __forceinline__ float bfhi(unsigned int u) {
  return __uint_as_float(u & 0xffff0000u);
}
// packed-f32 accumulate: 4x v_pk_fma_f32 instead of 8 scalar v_fma (contract=fast)
__device__ __forceinline__ void acc8v(f32x2_t* a, uint4 v, float nrm) {
  f32x2_t nn = {nrm, nrm};
  f32x2_t u0 = {bflo(v.x), bfhi(v.x)};
  f32x2_t u1 = {bflo(v.y), bfhi(v.y)};
  f32x2_t u2 = {bflo(v.z), bfhi(v.z)};
  f32x2_t u3 = {bflo(v.w), bfhi(v.w)};
  a[0] += nn * u0;
  a[1] += nn * u1;
  a[2] += nn * u2;
  a[3] += nn * u3;
}

// ---------------- fused front kernel ----------------
// blocks [0, PA_BLOCKS): edge partition into coarse buckets — LDS-only atomics,
//   one 8-B record {src | z<<17 | (dst&127)<<20, norm} per edge (src<2^17, z<8).
// blocks [PA_BLOCKS, +W0B_BLOCKS): w0b table build, SRC-INDEXED: row m holds
//   compose(bases0[:, h[m], :]) so gathers use row = src*8+z directly (no epw).
// blocks [.., +COMPOSE_BLOCKS): small composed weights

__global__ __launch_bounds__(256) void front_kernel(
    const int* __restrict__ r, const int* __restrict__ dst, const int* __restrict__ src,
    const int* __restrict__ h, const float* __restrict__ norm, int* __restrict__ tmpCur,
    uint2* __restrict__ tmpR, const float* __restrict__ bases0,
    const float* __restrict__ wcomp0, unsigned short* __restrict__ w0b,
    const float* __restrict__ wcomp1, const float* __restrict__ bases1,
    const float* __restrict__ loop1, const float* __restrict__ wcomp2,
    const float* __restrict__ bases2, const float* __restrict__ loop2,
    unsigned short* __restrict__ w1big, unsigned short* __restrict__ w2t,
    unsigned short* __restrict__ loop2t) {
  __shared__ int hist[NC];
  __shared__ int run[NC];
  int tid = threadIdx.x;
  if (blockIdx.x < PA_BLOCKS) {
    int base = blockIdx.x * CHUNK_E;
    for (int i = tid; i < NC; i += 256) hist[i] = 0;
    __syncthreads();
    int dcache[EPT];
#pragma unroll
    for (int j = 0; j < EPT; ++j) {
      int e = base + tid + j * 256;
      dcache[j] = (e < EE) ? dst[e] : -1;
      if (e < EE) atomicAdd(&hist[dcache[j] >> 7], 1);
    }
    __syncthreads();
    for (int i = tid; i < NC; i += 256)
      if (hist[i] > 0) run[i] = i * CAP + atomicAdd(&tmpCur[i], hist[i]);
    __syncthreads();
#pragma unroll
    for (int j = 0; j < EPT; ++j) {
      int e = base + tid + j * 256;
      if (e < EE) {
        int d = dcache[j], z = r[e];
        int c = d >> 7;
        int pos = atomicAdd(&run[c], 1);
        uint2 rec;
        rec.x = (unsigned)src[e] | ((unsigned)z << 17) | ((unsigned)(d & 127) << 20);
        rec.y = __float_as_uint(norm[e]);
        tmpR[pos] = rec;
      }
    }
    return;
  }
  int bx = blockIdx.x - PA_BLOCKS;
  if (bx < W0B_BLOCKS) {
    // ---- w0b table [m][z][f], src-indexed via h: 16 floats/thread ----
    int idx = bx * 256 + tid;  // m*8 + c16
    int m = idx >> 3, c16 = idx & 7;
    if (m >= NN) return;
    int hm = h[m];
    float4 a[BB][4];
#pragma unroll
    for (int b = 0; b < BB; ++b) {
      const float4* sp = (const float4*)(bases0 + ((size_t)b * NN + hm) * HH + c16 * 16);
      a[b][0] = sp[0];
      a[b][1] = sp[1];
      a[b][2] = sp[2];
      a[b][3] = sp[3];
    }
    uint4* orow = (uint4*)w0b + (size_t)m * 128 + c16 * 2;
#pragma unroll
    for (int z = 0; z < RRL; ++z) {
      float c0 = wcomp0[z * BB + 0], c1 = wcomp0[z * BB + 1];
      float c2 = wcomp0[z * BB + 2], c3 = wcomp0[z * BB + 3];
      float e[16];
#pragma unroll
      for (int q = 0; q < 4; ++q) {
        e[q * 4 + 0] = c0 * a[0][q].x + c1 * a[1][q].x + c2 * a[2][q].x + c3 * a[3][q].x;
        e[q * 4 + 1] = c0 * a[0][q].y + c1 * a[1][q].y + c2 * a[2][q].y + c3 * a[3][q].y;
        e[q * 4 + 2] = c0 * a[0][q].z + c1 * a[1][q].z + c2 * a[2][q].z + c3 * a[3][q].z;
        e[q * 4 + 3] = c0 * a[0][q].w + c1 * a[1][q].w + c2 * a[2][q].w + c3 * a[3][q].w;
      }
      uint4 pk0, pk1;
      pk0.x = ((unsigned)f2bf(e[1]) << 16) | f2bf(e[0]);
      pk0.y = ((unsigned)f2bf(e[3]) << 16) | f2bf(e[2]);
      pk0.z = ((unsigned)f2bf(e[5]) << 16) | f2bf(e[4]);
      pk0.w = ((unsigned)f2bf(e[7]) << 16) | f2bf(e[6]);
      pk1.x = ((unsigned)f2bf(e[9]) << 16) | f2bf(e[8]);
      pk1.y = ((unsigned)f2bf(e[11]) << 16) | f2bf(e[10]);
      pk1.z = ((unsigned)f2bf(e[13]) << 16) | f2bf(e[12]);
      pk1.w = ((unsigned)f2bf(e[15]) << 16) | f2bf(e[14]);
      orow[z * 16] = pk0;
      orow[z * 16 + 1] = pk1;
    }
    return;
  }
  // ---- composed small weights ----
  int idx = (bx - W0B_BLOCKS) * 256 + tid;
  if (idx < HH * KBIG) {  // w1big[n][k]
    int n = idx / KBIG, k = idx - n * KBIG;
    float a;
    if (k < 1024) {
      int z = k >> 7, kk = k & 127;
      a = 0.f;
#pragma unroll
      for (int b = 0; b < BB; ++b)
        a += wcomp1[z * BB + b] * bases1[((size_t)b * HH + kk) * HH + n];
    } else {
      int kk = k - 1024;
      a = loop1[kk * HH + n];
    }
    w1big[idx] = f2bf(a);
    return;
  }
  int j = idx - HH * KBIG;
  if (j < RRL * CC * HH) {  // w2t[z][n][k]
    int z = j >> 11;
    int rem = j & 2047;
    int n = rem >> 7, k = rem & 127;
    float a = 0.f;
#pragma unroll
    for (int b = 0; b < BB; ++b)
      a += wcomp2[z * BB + b] * bases2[((size_t)b * HH + k) * CC + n];
    w2t[j] = f2bf(a);
    return;
  }
  j -= RRL * CC * HH;
  if (j < CC * HH) {  // loop2t[n][k]
    int n = j >> 7, k = j & 127;
    loop2t[j] = f2bf(loop2[k * CC + n]);
  }
}

// ---------------- placeB: per-bucket local counting sort ----------------
// One block per coarse bucket (1024 keys, ~2046 records). lk = (packed>>17)&1023
// == (dst&127)*8 + z by bit layout. Single ep1 output stream (src|z<<24, norm);
// both gather layers derive their table row as src*8+z from it.

__global__ __launch_bounds__(256) void placeB_kernel(const int* __restrict__ tmpCur,
                                                     const uint2* __restrict__ tmpR,
                                                     int* __restrict__ off2,
                                                     uint2* __restrict__ ep1) {
  __shared__ int lh[KPB];
  __shared__ int sums[256];
  const int c = blockIdx.x;
  const int tid = threadIdx.x;
  const int cnt = tmpCur[c];
  const int base = c * CAP;
  // coarse base = sum of tmpCur[0..c-1]
  int partial = 0;
  for (int j = tid; j < c; j += 256) partial += tmpCur[j];
  sums[tid] = partial;
  __syncthreads();
  for (int o = 1; o < 256; o <<= 1) {
    int t = (tid >= o) ? sums[tid - o] : 0;
    __syncthreads();
    sums[tid] += t;
    __syncthreads();
  }
  const int cbase = sums[255];
  // local histogram
  for (int j = tid; j < KPB; j += 256) lh[j] = 0;
  __syncthreads();
  for (int i = tid; i < cnt; i += 256)
    atomicAdd(&lh[(tmpR[base + i].x >> 17) & 1023], 1);
  __syncthreads();
  // exclusive prefix over lh (4 per thread)
  int v0 = lh[tid * 4], v1 = lh[tid * 4 + 1], v2 = lh[tid * 4 + 2], v3 = lh[tid * 4 + 3];
  int s = v0 + v1 + v2 + v3;
  sums[tid] = s;
  __syncthreads();
  for (int o = 1; o < 256; o <<= 1) {
    int t = (tid >= o) ? sums[tid - o] : 0;
    __syncthreads();
    sums[tid] += t;
    __syncthreads();
  }
  int run = sums[tid] - s;
  lh[tid * 4] = run;
  lh[tid * 4 + 1] = run + v0;
  lh[tid * 4 + 2] = run + v0 + v1;
  lh[tid * 4 + 3] = run + v0 + v1 + v2;
  // write off2 slice
  const int key0 = c * KPB;
#pragma unroll
  for (int j = 0; j < 4; ++j) {
    int key = key0 + tid * 4 + j;
    if (key < NT) off2[key] = cbase + lh[tid * 4 + j];
  }
  if (c == 0 && tid == 0) off2[NT] = EE;
  __syncthreads();
  // place (lh becomes the cursor)
  for (int i = tid; i < cnt; i += 256) {
    uint2 rec = tmpR[base + i];
    int lk = (rec.x >> 17) & 1023;
    int pos = cbase + atomicAdd(&lh[lk], 1);
    unsigned sv = rec.x & 0x1FFFFu, z = (rec.x >> 17) & 7u;
    ep1[pos] = (uint2){sv | (z << 24), rec.y};
  }
}

// ---------------- layer 0: wave/dst, merged range, 4 slots x 16 lanes, 2-deep ----------------
// row = src*8 + z from ep1 (w0b is src-indexed; same formula as l1_seg).

__global__ __launch_bounds__(256) void l0_seg_kernel(
    const int* __restrict__ h, const int* __restrict__ off2, const uint2* __restrict__ ep1,
    const unsigned short* __restrict__ w0b, const float* __restrict__ loop0,
    const float* __restrict__ bias0, unsigned short* __restrict__ x1b) {
  int lane = threadIdx.x & 63;
  int n = blockIdx.x * 4 + (threadIdx.x >> 6);
  if (n >= NP) return;
  const int g = lane >> 4;
  const int t = lane & 15;
  f32x2_t acc[4];
#pragma unroll
  for (int j = 0; j < 4; ++j) acc[j] = (f32x2_t){0.f, 0.f};

  if (n < NN) {
    int beg = off2[n * RRL];
    int end = off2[n * RRL + RRL];
    int i = beg + g;
    uint2 p0 = {0u, 0u}, p1 = {0u, 0u};
    if (i < end) p0 = ep1[i];
    if (i + 4 < end) p1 = ep1[i + 4];
    unsigned r0 = (p0.x & 0xFFFFFFu) * 8u + (p0.x >> 24);
    unsigned r1 = (p1.x & 0xFFFFFFu) * 8u + (p1.x >> 24);
    while (i < end) {
      uint2 q0 = {0u, 0u}, q1 = {0u, 0u};
      if (i + 8 < end) q0 = ep1[i + 8];
      if (i + 12 < end) q1 = ep1[i + 12];
      uint4 va = *(const uint4*)(w0b + (size_t)r0 * HH + t * 8);
      uint4 vb = *(const uint4*)(w0b + (size_t)r1 * HH + t * 8);
      acc8v(acc, va, __uint_as_float(p0.y));
      acc8v(acc, vb, __uint_as_float(p1.y));
      i += 8;
      p0 = q0;
      p1 = q1;
      r0 = (q0.x & 0xFFFFFFu) * 8u + (q0.x >> 24);
      r1 = (q1.x & 0xFFFFFFu) * 8u + (q1.x >> 24);
    }
  }
  float* af = (float*)acc;
#pragma unroll
  for (int j = 0; j < 8; ++j) {
    af[j] += __shfl_xor(af[j], 16, 64);
    af[j] += __shfl_xor(af[j], 32, 64);
  }
  if (g != 0) return;
  uint4 o = {0u, 0u, 0u, 0u};
  if (n < NN) {
    int hn = h[n];
    float4 l0v = ((const float4*)(loop0 + (size_t)hn * HH))[t * 2];
    float4 l1v = ((const float4*)(loop0 + (size_t)hn * HH))[t * 2 + 1];
    float4 b0v = ((const float4*)bias0)[t * 2];
    float4 b1v = ((const float4*)bias0)[t * 2 + 1];
    float e0 = fmaxf(af[0] + l0v.x + b0v.x, 0.f);
    float e1 = fmaxf(af[1] + l0v.y + b0v.y, 0.f);
    float e2 = fmaxf(af[2] + l0v.z + b0v.z, 0.f);
    float e3 = fmaxf(af[3] + l0v.w + b0v.w, 0.f);
    float e4 = fmaxf(af[4] + l1v.x + b1v.x, 0.f);
    float e5 = fmaxf(af[5] + l1v.y + b1v.y, 0.f);
    float e6 = fmaxf(af[6] + l1v.z + b1v.z, 0.f);
    float e7 = fmaxf(af[7] + l1v.w + b1v.w, 0.f);
    o.x = ((unsigned)f2bf(e1) << 16) | f2bf(e0);
    o.y = ((unsigned)f2bf(e3) << 16) | f2bf(e2);
    o.z = ((unsigned)f2bf(e5) << 16) | f2bf(e4);
    o.w = ((unsigned)f2bf(e7) << 16) | f2bf(e6);
  }
  *(uint4*)(x1b + (size_t)n * HH + t * 8) = o;
}

// ---------------- layer 1 transform GEMM: T[m][z][f] = x1b @ W_z^T, t9f = x1b @ loop1^T ----

__global__ __launch_bounds__(256) void t1_gemm_kernel(const unsigned short* __restrict__ x1b,
                                                      const unsigned short* __restrict__ w1big,
                                                      unsigned short* __restrict__ T,
                                                      float* __restrict__ t9f) {
  constexpr int LP = 136;
  __shared__ unsigned short Alds[128 * LP];
  __shared__ unsigned short Blds[128 * LP];
  const int row0 = blockIdx.x * 128;
  const int tid = threadIdx.x;
  const int w = tid >> 6, lane = tid & 63;
  const int quad = lane >> 4, l15 = lane & 15;
  const int rb = w * 32;

#pragma unroll
  for (int it = 0; it < 8; ++it) {
    int flat = tid + it * 256;
    int row = flat >> 4, c8 = flat & 15;
    *(uint4*)(&Alds[row * LP + c8 * 8]) =
        *(const uint4*)(x1b + (size_t)(row0 + row) * 128 + c8 * 8);
  }

  for (int z = 0; z < 9; ++z) {
    __syncthreads();  // prior readers of Blds done (covers A load on z=0)
#pragma unroll
    for (int it = 0; it < 8; ++it) {
      int flat = tid + it * 256;
      int row = flat >> 4, c8 = flat & 15;
      *(uint4*)(&Blds[row * LP + c8 * 8]) =
          *(const uint4*)(w1big + (size_t)row * KBIG + z * 128 + c8 * 8);
    }
    __syncthreads();
    f32x4_t acc[2][8];
#pragma unroll
    for (int rt = 0; rt < 2; ++rt)
#pragma unroll
      for (int ct = 0; ct < 8; ++ct) acc[rt][ct] = (f32x4_t){0.f, 0.f, 0.f, 0.f};
#pragma unroll
    for (int ks = 0; ks < 4; ++ks) {
      int ko = ks * 32 + quad * 8;
      bf16x8_t af[2], bfr[8];
#pragma unroll
      for (int rt = 0; rt < 2; ++rt)
        af[rt] = *(const bf16x8_t*)(&Alds[(rb + rt * 16 + l15) * LP + ko]);
#pragma unroll
      for (int ct = 0; ct < 8; ++ct)
        bfr[ct] = *(const bf16x8_t*)(&Blds[(ct * 16 + l15) * LP + ko]);
#pragma unroll
      for (int rt = 0; rt < 2; ++rt)
#pragma unroll
        for (int ct = 0; ct < 8; ++ct)
          acc[rt][ct] =
              __builtin_amdgcn_mfma_f32_16x16x32_bf16(af[rt], bfr[ct], acc[rt][ct], 0, 0, 0);
    }
    if (z < 8) {
#pragma unroll
      for (int rt = 0; rt < 2; ++rt)
#pragma unroll
        for (int ct = 0; ct < 8; ++ct) {
          int f = ct * 16 + l15;
#pragma unroll
          for (int i = 0; i < 4; ++i) {
            int m = row0 + rb + rt * 16 + quad * 4 + i;
            T[((size_t)m * 8 + z) * 128 + f] = f2bf(acc[rt][ct][i]);
          }
        }
    } else {
#pragma unroll
      for (int rt = 0; rt < 2; ++rt)
#pragma unroll
        for (int ct = 0; ct < 8; ++ct) {
          int f = ct * 16 + l15;
#pragma unroll
          for (int i = 0; i < 4; ++i) {
            int m = row0 + rb + rt * 16 + quad * 4 + i;
            t9f[(size_t)m * 128 + f] = acc[rt][ct][i];
          }
        }
    }
  }
}

// ---------------- layer 1 gather: l0_seg clone over the T table ----------------

__global__ __launch_bounds__(256) void l1_seg_kernel(
    const int* __restrict__ off2, const uint2* __restrict__ ep1,
    const unsigned short* __restrict__ T, const float* __restrict__ t9f,
    const float* __restrict__ bias1, unsigned short* __restrict__ x2b) {
  int lane = threadIdx.x & 63;
  int n = blockIdx.x * 4 + (threadIdx.x >> 6);
  if (n >= NP) return;
  const int g = lane >> 4;
  const int t = lane & 15;
  f32x2_t acc[4];
#pragma unroll
  for (int j = 0; j < 4; ++j) acc[j] = (f32x2_t){0.f, 0.f};

  if (n < NN) {
    int beg = off2[n * RRL];
    int end = off2[n * RRL + RRL];
    int i = beg + g;
    uint2 p0 = {0u, 0u}, p1 = {0u, 0u};
    if (i < end) p0 = ep1[i];
    if (i + 4 < end) p1 = ep1[i + 4];
    unsigned r0 = (p0.x & 0xFFFFFFu) * 8u + (p0.x >> 24);
    unsigned r1 = (p1.x & 0xFFFFFFu) * 8u + (p1.x >> 24);
    while (i < end) {
      uint2 q0 = {0u, 0u}, q1 = {0u, 0u};
      if (i + 8 < end) q0 = ep1[i + 8];
      if (i + 12 < end) q1 = ep1[i + 12];
      uint4 va = *(const uint4*)(T + (size_t)r0 * HH + t * 8);
      uint4 vb = *(const uint4*)(T + (size_t)r1 * HH + t * 8);
      acc8v(acc, va, __uint_as_float(p0.y));
      acc8v(acc, vb, __uint_as_float(p1.y));
      i += 8;
      p0 = q0;
      p1 = q1;
      r0 = (q0.x & 0xFFFFFFu) * 8u + (q0.x >> 24);
      r1 = (q1.x & 0xFFFFFFu) * 8u + (q1.x >> 24);
    }
  }
  float* af = (float*)acc;
#pragma unroll
  for (int j = 0; j < 8; ++j) {
    af[j] += __shfl_xor(af[j], 16, 64);
    af[j] += __shfl_xor(af[j], 32, 64);
  }
  if (g != 0) return;
  uint4 o = {0u, 0u, 0u, 0u};
  if (n < NN) {
    float4 l0v = ((const float4*)(t9f + (size_t)n * HH))[t * 2];
    float4 l1v = ((const float4*)(t9f + (size_t)n * HH))[t * 2 + 1];
    float4 b0v = ((const float4*)bias1)[t * 2];
    float4 b1v = ((const float4*)bias1)[t * 2 + 1];
    float e0 = fmaxf(af[0] + l0v.x + b0v.x, 0.f);
    float e1 = fmaxf(af[1] + l0v.y + b0v.y, 0.f);
    float e2 = fmaxf(af[2] + l0v.z + b0v.z, 0.f);
    float e3 = fmaxf(af[3] + l0v.w + b0v.w, 0.f);
    float e4 = fmaxf(af[4] + l1v.x + b1v.x, 0.f);
    float e5 = fmaxf(af[5] + l1v.y + b1v.y, 0.f);
    float e6 = fmaxf(af[6] + l1v.z + b1v.z, 0.f);
    float e7 = fmaxf(af[7] + l1v.w + b1v.w, 0.f);
    o.x = ((unsigned)f2bf(e1) << 16) | f2bf(e0);
    o.y = ((unsigned)f2bf(e3) << 16) | f2bf(e2);
    o.z = ((unsigned)f2bf(e5) << 16) | f2bf(e4);
    o.w = ((unsigned)f2bf(e7) << 16) | f2bf(e6);
  }
  *(uint4*)(x2b + (size_t)n * HH + t * 8) = o;
}

// ---------------- layer-2 transform: one pass over x2b, all 8 rels + self-loop ----------------

__global__ __launch_bounds__(256) void l2_trans_kernel(
    const unsigned short* __restrict__ x2b, const unsigned short* __restrict__ w2t,
    const unsigned short* __restrict__ loop2t, const float* __restrict__ bias2,
    unsigned short* __restrict__ trans2, float* __restrict__ out) {
  constexpr int LP = 136;
  __shared__ unsigned short Alds[128 * LP];
  __shared__ unsigned short Blds[9][16 * LP];
  const int row0 = blockIdx.x * 128;
  const int tid = threadIdx.x;

#pragma unroll
  for (int it = 0; it < 8; ++it) {
    int flat = tid + it * 256;
    int row = flat >> 4, c8 = flat & 15;
    *(uint4*)(&Alds[row * LP + c8 * 8]) =
        *(const uint4*)(x2b + ((size_t)(row0 + row)) * 128 + c8 * 8);
  }
  {
    int row = tid >> 4, c8 = tid & 15;
#pragma unroll
    for (int z = 0; z < 9; ++z) {
      const unsigned short* B = (z < 8) ? w2t + (size_t)z * CC * HH : loop2t;
      *(uint4*)(&Blds[z][row * LP + c8 * 8]) = *(const uint4*)(B + row * 128 + c8 * 8);
    }
  }
  __syncthreads();

  const int w = tid >> 6, lane = tid & 63;
  const int quad = lane >> 4, l15 = lane & 15;
  const int rb = w * 32;

  for (int z = 0; z < 9; ++z) {
    f32x4_t acc[2];
    acc[0] = (f32x4_t){0.f, 0.f, 0.f, 0.f};
    acc[1] = (f32x4_t){0.f, 0.f, 0.f, 0.f};
#pragma unroll
    for (int ks = 0; ks < 4; ++ks) {
      int ko = ks * 32 + quad * 8;
      bf16x8_t af0 = *(const bf16x8_t*)(&Alds[(rb + l15) * LP + ko]);
      bf16x8_t af1 = *(const bf16x8_t*)(&Alds[(rb + 16 + l15) * LP + ko]);
      bf16x8_t bfr = *(const bf16x8_t*)(&Blds[z][l15 * LP + ko]);
      acc[0] = __builtin_amdgcn_mfma_f32_16x16x32_bf16(af0, bfr, acc[0], 0, 0, 0);
      acc[1] = __builtin_amdgcn_mfma_f32_16x16x32_bf16(af1, bfr, acc[1], 0, 0, 0);
    }
    if (z < 8) {
      unsigned short* ob = trans2 + (size_t)z * NP * CC;
#pragma unroll
      for (int rt = 0; rt < 2; ++rt)
#pragma unroll
        for (int i = 0; i < 4; ++i) {
          int m = row0 + rb + rt * 16 + quad * 4 + i;
          ob[(size_t)m * CC + l15] = f2bf(acc[rt][i]);
        }
    } else {
      float bv = bias2[l15];
#pragma unroll
      for (int rt = 0; rt < 2; ++rt)
#pragma unroll
        for (int i = 0; i < 4; ++i) {
          int m = row0 + rb + rt * 16 + quad * 4 + i;
          if (m < NN) out[(size_t)m * CC + l15] = acc[rt][i] + bv;
        }
    }
  }
}

// ---------------- layer 2 gather: wave/dst, merged range, 8 slots x 8 lanes, 2x unroll ----------------

__global__ __launch_bounds__(256) void l2_seg_kernel(const int* __restrict__ off2,
                                                     const uint2* __restrict__ ep1,
                                                     const unsigned short* __restrict__ trans2,
                                                     float* __restrict__ outp) {
  int lane = threadIdx.x & 63;
  int n = blockIdx.x * 4 + (threadIdx.x >> 6);
  if (n >= NN) return;
  const int g = lane >> 3;
  const int t = lane & 7;
  float a0 = 0.f, a1 = 0.f;
  int beg = off2[n * RRL];
  int end = off2[n * RRL + RRL];
  int i = beg + g;
  uint2 p0 = {0u, 0u}, p1 = {0u, 0u};
  if (i < end) p0 = ep1[i];
  if (i + 8 < end) p1 = ep1[i + 8];
  while (i < end) {
    uint2 q0 = {0u, 0u}, q1 = {0u, 0u};
    if (i + 16 < end) q0 = ep1[i + 16];
    if (i + 24 < end) q1 = ep1[i + 24];
    unsigned s0 = p0.x & 0xFFFFFFu, z0 = p0.x >> 24;
    unsigned s1 = p1.x & 0xFFFFFFu, z1 = p1.x >> 24;
    unsigned int u0 =
        *(const unsigned int*)(trans2 + ((size_t)z0 * NP + s0) * CC + t * 2);
    unsigned int u1 =
        *(const unsigned int*)(trans2 + ((size_t)z1 * NP + s1) * CC + t * 2);
    float na = __uint_as_float(p0.y), nb = __uint_as_float(p1.y);
    a0 = fmaf(na, bflo(u0), a0);
    a1 = fmaf(na, bfhi(u0), a1);
    a0 = fmaf(nb, bflo(u1), a0);
    a1 = fmaf(nb, bfhi(u1), a1);
    i += 16;
    p0 = q0;
    p1 = q1;
  }
  a0 += __shfl_xor(a0, 8, 64);
  a0 += __shfl_xor(a0, 16, 64);
  a0 += __shfl_xor(a0, 32, 64);
  a1 += __shfl_xor(a1, 8, 64);
  a1 += __shfl_xor(a1, 16, 64);
  a1 += __shfl_xor(a1, 32, 64);
  if (g != 0) return;
  float2* o = (float2*)(outp + (size_t)n * CC) + t;
  float2 cv = *o;
  cv.x += a0;
  cv.y += a1;
  *o = cv;
}

// ---------------- launch ----------------

extern "C" void kernel_launch(void* const* d_in, const int* in_sizes, int n_in,
                              void* d_out, int out_size, void* d_ws, size_t ws_size,
                              hipStream_t stream) {
  const int* src = (const int*)d_in[0];
  const int* dst = (const int*)d_in[1];
  const int* h = (const int*)d_in[2];
  const int* r = (const int*)d_in[3];
  const float* norm = (const float*)d_in[4];
  const float* bases0 = (const float*)d_in[5];
  const float* wcomp0 = (const float*)d_in[6];
  const float* loop0 = (const float*)d_in[7];
  const float* bias0 = (const float*)d_in[8];
  const float* bases1 = (const float*)d_in[9];
  const float* wcomp1 = (const float*)d_in[10];
  const float* loop1 = (const float*)d_in[11];
  const float* bias1 = (const float*)d_in[12];
  const float* bases2 = (const float*)d_in[13];
  const float* wcomp2 = (const float*)d_in[14];
  const float* loop2 = (const float*)d_in[15];
  const float* bias2 = (const float*)d_in[16];
  float* out = (float*)d_out;

  char* p = (char*)d_ws;
  auto alloc = [&](size_t bytes) {
    char* q = p;
    p += (bytes + 255) & ~(size_t)255;
    return q;
  };
  unsigned short* x1b = (unsigned short*)alloc((size_t)NP * HH * 2);
  unsigned short* x2b = (unsigned short*)alloc((size_t)NP * HH * 2);
  unsigned short* trans2 = (unsigned short*)alloc((size_t)RRL * NP * CC * 2);
  unsigned short* w1big = (unsigned short*)alloc((size_t)HH * KBIG * 2);
  unsigned short* w2t = (unsigned short*)alloc((size_t)RRL * CC * HH * 2);
  unsigned short* loop2t = (unsigned short*)alloc((size_t)CC * HH * 2);
  float* t9f = (float*)alloc((size_t)NP * HH * 4);
  uint2* ep1 = (uint2*)alloc((size_t)EE * 8);
  uint2* tmpR = (uint2*)alloc((size_t)NC * CAP * 8);
  int* off2 = (int*)alloc((size_t)(NT + 1) * 4);
  int* tmpCur = (int*)alloc(2048);  // 512 ints >= NC=391
  // BIG: w0b [NN][8][128] bf16 during layer 0, then reused as T [NP][8][128] bf16
  unsigned short* BIG = (unsigned short*)alloc((size_t)RRL * NP * HH * 2);

  // ---- fused front: edge partition (LDS-only atomics) + weight prep ----
  hipMemsetAsync(tmpCur, 0, 2048, stream);
  front_kernel<<<FRONT_BLOCKS, 256, 0, stream>>>(
      r, dst, src, h, norm, tmpCur, tmpR, bases0, wcomp0, BIG, wcomp1, bases1, loop1,
      wcomp2, bases2, loop2, w1big, w2t, loop2t);

  // ---- per-bucket local counting sort: off2 + ep1 in one kernel ----
  placeB_kernel<<<NC, 256, 0, stream>>>(tmpCur, tmpR, off2, ep1);

  // ---- layer 0 ----
  l0_seg_kernel<<<NP / 4, 256, 0, stream>>>(h, off2, ep1, BIG, loop0, bias0, x1b);

  // ---- layer 1: transform-then-gather (T overwrites w0b in BIG) ----
  t1_gemm_kernel<<<NP / 128, 256, 0, stream>>>(x1b, w1big, BIG, t9f);
  l1_seg_kernel<<<NP / 4, 256, 0, stream>>>(off2, ep1, BIG, t9f, bias1, x2b);

  // ---- layer 2 ----
  l2_trans_kernel<<<NP / 128, 256, 0, stream>>>(x2b, w2t, loop2t, bias2, trans2, out);
  l2_seg_kernel<<<(NN + 3) / 4, 256, 0, stream>>>(off2, ep1, trans2, out);
}